// Round 1
// baseline (339.370 us; speedup 1.0000x reference)
//
#include <hip/hip_runtime.h>
#include <math.h>

#define CDIM 128
#define HW   4096
#define HEADS 4
#define HD   32

// ---------------- RMSNorm (channel axis), two tensors via blockIdx.y ----------------
__global__ __launch_bounds__(256) void rmsnorm2(
    const float* __restrict__ x0, const float* __restrict__ w0, float* __restrict__ o0,
    const float* __restrict__ x1, const float* __restrict__ w1, float* __restrict__ o1) {
  const float* x; const float* w; float* o;
  if (blockIdx.y == 0) { x = x0; w = w0; o = o0; }
  else                 { x = x1; w = w1; o = o1; }
  int t  = threadIdx.x;
  int pl = t & 63;        // pixel within block
  int g  = t >> 6;        // channel group 0..3 (32 channels each)
  int gp = blockIdx.x * 64 + pl;          // 0..8191 = b*4096 + pix
  size_t base = (size_t)(gp >> 12) * CDIM * HW + (gp & 4095);
  const float* xb = x + base;
  float*       ob = o + base;
  float vals[32];
  float ss = 0.f;
#pragma unroll
  for (int j = 0; j < 32; ++j) {
    float v = xb[(size_t)(g * 32 + j) * HW];
    vals[j] = v;
    ss += v * v;
  }
  __shared__ float sh[4][64];
  sh[g][pl] = ss;
  __syncthreads();
  float tot = sh[0][pl] + sh[1][pl] + sh[2][pl] + sh[3][pl];
  float inv = rsqrtf(tot * (1.0f / CDIM) + 1e-8f);
#pragma unroll
  for (int j = 0; j < 32; ++j) {
    int c = g * 32 + j;
    ob[(size_t)c * HW] = vals[j] * inv * w[c];
  }
}

// ---------------- conv1x1 = GEMM  out[o,p] = sum_i W[o,i]*X[i,p] + b[o] ----------------
// grid: (P/64, Cout/64, B), block 256.  BM=BN=64, BK=64.
template <int GELU, int RES>
__global__ __launch_bounds__(256) void conv1x1_k(
    const float* __restrict__ X, const float* __restrict__ W,
    const float* __restrict__ bias, const float* __restrict__ res,
    float* __restrict__ out, int Cin, int Cout) {
  int b = blockIdx.z;
  const float* Xb   = X + (size_t)b * Cin * HW;
  float*       outb = out + (size_t)b * Cout * HW;
  const float* resb = res ? res + (size_t)b * Cout * HW : nullptr;
  int p0 = blockIdx.x * 64;
  int o0 = blockIdx.y * 64;
  __shared__ float sW[64][65];  // [o][k]
  __shared__ float sX[64][65];  // [k][p]
  int t  = threadIdx.x;
  int tx = t & 15;   // pixel group
  int ty = t >> 4;   // out group
  float acc[4][4] = {{0.f}};
  for (int k0 = 0; k0 < Cin; k0 += 64) {
#pragma unroll
    for (int i = 0; i < 16; ++i) {            // 4096 elems, 256 thr
      int idx = t + i * 256;
      int oo = idx >> 6, kk = idx & 63;
      sW[oo][kk] = W[(size_t)(o0 + oo) * Cin + k0 + kk];
    }
#pragma unroll
    for (int i = 0; i < 16; ++i) {
      int idx = t + i * 256;
      int kk = idx >> 6, pp = idx & 63;
      sX[kk][pp] = Xb[(size_t)(k0 + kk) * HW + p0 + pp];
    }
    __syncthreads();
#pragma unroll 8
    for (int kk = 0; kk < 64; ++kk) {
      float a0 = sW[ty * 4 + 0][kk];
      float a1 = sW[ty * 4 + 1][kk];
      float a2 = sW[ty * 4 + 2][kk];
      float a3 = sW[ty * 4 + 3][kk];
      float b0 = sX[kk][tx * 4 + 0];
      float b1 = sX[kk][tx * 4 + 1];
      float b2 = sX[kk][tx * 4 + 2];
      float b3 = sX[kk][tx * 4 + 3];
      acc[0][0] += a0 * b0; acc[0][1] += a0 * b1; acc[0][2] += a0 * b2; acc[0][3] += a0 * b3;
      acc[1][0] += a1 * b0; acc[1][1] += a1 * b1; acc[1][2] += a1 * b2; acc[1][3] += a1 * b3;
      acc[2][0] += a2 * b0; acc[2][1] += a2 * b1; acc[2][2] += a2 * b2; acc[2][3] += a2 * b3;
      acc[3][0] += a3 * b0; acc[3][1] += a3 * b1; acc[3][2] += a3 * b2; acc[3][3] += a3 * b3;
    }
    __syncthreads();
  }
#pragma unroll
  for (int m = 0; m < 4; ++m) {
    int o = o0 + ty * 4 + m;
    float bv = bias[o];
#pragma unroll
    for (int n = 0; n < 4; ++n) {
      int p = p0 + tx * 4 + n;
      float v = acc[m][n] + bv;
      if (GELU) v = 0.5f * v * (1.0f + erff(v * 0.70710678118654752f));
      if (RES)  v += resb[(size_t)o * HW + p];
      outb[(size_t)o * HW + p] = v;
    }
  }
}

// ---------------- neighborhood attention: one wave per (row, head, batch) ----------------
__global__ __launch_bounds__(64) void nattn(
    const float* __restrict__ Q, const float* __restrict__ K,
    const float* __restrict__ V, float* __restrict__ O) {
  __shared__ float sS[49][64];
  const int x = threadIdx.x;      // 0..63 == W coordinate
  const int y = blockIdx.x;       // row
  const int h = blockIdx.y;       // head
  const int b = blockIdx.z;
  const size_t base = (size_t)(b * CDIM + h * HD) * HW;
  const float* Qp = Q + base + y * 64 + x;
  float q[HD];
#pragma unroll
  for (int d = 0; d < HD; ++d) q[d] = Qp[(size_t)d * HW];
  const float scale = 0.17677669529663687f;  // 32^-0.5
  float m = -1e30f;
  for (int dy = -3; dy <= 3; ++dy) {
    int ny  = y + dy;
    int nyc = min(max(ny, 0), 63);
    bool vy = (ny == nyc);
    for (int dx = -3; dx <= 3; ++dx) {
      int nx  = x + dx;
      int nxc = min(max(nx, 0), 63);
      bool val = vy && (nx == nxc);
      const float* Kp = K + base + nyc * 64 + nxc;
      float acc = 0.f;
#pragma unroll
      for (int d = 0; d < HD; ++d) acc += q[d] * Kp[(size_t)d * HW];
      float sc = val ? acc * scale : -1e30f;
      sS[(dy + 3) * 7 + (dx + 3)][x] = sc;
      m = fmaxf(m, sc);
    }
  }
  // block == 1 wave, each thread reads only its own column; no barrier needed.
  float sum = 0.f;
  float o[HD];
#pragma unroll
  for (int d = 0; d < HD; ++d) o[d] = 0.f;
  for (int dy = -3; dy <= 3; ++dy) {
    int nyc = min(max(y + dy, 0), 63);
    for (int dx = -3; dx <= 3; ++dx) {
      int nxc = min(max(x + dx, 0), 63);
      float p = __expf(sS[(dy + 3) * 7 + (dx + 3)][x] - m);  // invalid -> exp(-1e30-m)=0
      sum += p;
      const float* Vp = V + base + nyc * 64 + nxc;
#pragma unroll
      for (int d = 0; d < HD; ++d) o[d] += p * Vp[(size_t)d * HW];
    }
  }
  float inv = 1.0f / sum;
  float* Op = O + base + y * 64 + x;
#pragma unroll
  for (int d = 0; d < HD; ++d) Op[(size_t)d * HW] = o[d] * inv;
}

// ---------------- launch ----------------
extern "C" void kernel_launch(void* const* d_in, const int* in_sizes, int n_in,
                              void* d_out, int out_size, void* d_ws, size_t ws_size,
                              hipStream_t stream) {
  const float* z   = (const float*)d_in[0];
  const float* h   = (const float*)d_in[1];
  const float* wzn = (const float*)d_in[2];
  const float* whn = (const float*)d_in[3];
  const float* wq  = (const float*)d_in[4];
  const float* bq  = (const float*)d_in[5];
  const float* wk  = (const float*)d_in[6];
  const float* bk  = (const float*)d_in[7];
  const float* wv  = (const float*)d_in[8];
  const float* bv  = (const float*)d_in[9];
  const float* wo  = (const float*)d_in[10];
  const float* bo  = (const float*)d_in[11];
  const float* wfn = (const float*)d_in[12];
  const float* w1  = (const float*)d_in[13];
  const float* b1  = (const float*)d_in[14];
  const float* w2  = (const float*)d_in[15];
  const float* b2  = (const float*)d_in[16];
  float* out = (float*)d_out;
  float* ws  = (float*)d_ws;

  const size_t SLAB = 2u * 1024u * 1024u;  // 2M floats = 8 MB (one B*C*H*W tensor)
  float* ZN   = ws;             // z_norm, later attn-out
  float* HN   = ws + 1 * SLAB;  // h_norm, later ffn-norm
  float* Qb   = ws + 2 * SLAB;  // q, later ffn hidden (spans Qb..Kb: 2M floats needed)
  float* Kb   = ws + 3 * SLAB;
  float* Vb   = ws + 4 * SLAB;
  float* ZNEW = ws + 5 * SLAB;  // z + attn
  float* ATT  = ZN;
  float* FN   = HN;
  float* HID  = Qb;             // [B][256][HW] = 2M floats, fits Qb..Kb

  // 1. rmsnorm z and h
  rmsnorm2<<<dim3(128, 2), 256, 0, stream>>>(z, wzn, ZN, h, whn, HN);
  // 2. q/k/v projections
  conv1x1_k<0, 0><<<dim3(64, 2, 2), 256, 0, stream>>>(ZN, wq, bq, nullptr, Qb, 128, 128);
  conv1x1_k<0, 0><<<dim3(64, 2, 2), 256, 0, stream>>>(HN, wk, bk, nullptr, Kb, 128, 128);
  conv1x1_k<0, 0><<<dim3(64, 2, 2), 256, 0, stream>>>(HN, wv, bv, nullptr, Vb, 128, 128);
  // 3. neighborhood attention
  nattn<<<dim3(64, HEADS, 2), 64, 0, stream>>>(Qb, Kb, Vb, ATT);
  // 4. output projection + residual -> z_new
  conv1x1_k<0, 1><<<dim3(64, 2, 2), 256, 0, stream>>>(ATT, wo, bo, z, ZNEW, 128, 128);
  // 5. ffn rmsnorm
  rmsnorm2<<<dim3(128, 1), 256, 0, stream>>>(ZNEW, wfn, FN, ZNEW, wfn, FN);
  // 6. ffn up + exact gelu
  conv1x1_k<1, 0><<<dim3(64, 4, 2), 256, 0, stream>>>(FN, w1, b1, nullptr, HID, 128, 256);
  // 7. ffn down + residual -> out
  conv1x1_k<0, 1><<<dim3(64, 2, 2), 256, 0, stream>>>(HID, w2, b2, ZNEW, out, 256, 128);
}

// Round 2
// 110.145 us; speedup vs baseline: 3.0811x; 3.0811x over previous
//
#include <hip/hip_runtime.h>
#include <math.h>

#define CDIM 128
#define HW   4096
#define HEADS 4
#define HD   32

// ---------------- RMSNorm (channel axis), two tensors via blockIdx.y ----------------
__global__ __launch_bounds__(256) void rmsnorm2(
    const float* __restrict__ x0, const float* __restrict__ w0, float* __restrict__ o0,
    const float* __restrict__ x1, const float* __restrict__ w1, float* __restrict__ o1) {
  const float* x; const float* w; float* o;
  if (blockIdx.y == 0) { x = x0; w = w0; o = o0; }
  else                 { x = x1; w = w1; o = o1; }
  int t  = threadIdx.x;
  int pl = t & 63;
  int g  = t >> 6;
  int gp = blockIdx.x * 64 + pl;
  size_t base = (size_t)(gp >> 12) * CDIM * HW + (gp & 4095);
  const float* xb = x + base;
  float*       ob = o + base;
  float vals[32];
  float ss = 0.f;
#pragma unroll
  for (int j = 0; j < 32; ++j) {
    float v = xb[(size_t)(g * 32 + j) * HW];
    vals[j] = v;
    ss += v * v;
  }
  __shared__ float sh[4][64];
  sh[g][pl] = ss;
  __syncthreads();
  float tot = sh[0][pl] + sh[1][pl] + sh[2][pl] + sh[3][pl];
  float inv = rsqrtf(tot * (1.0f / CDIM) + 1e-8f);
#pragma unroll
  for (int j = 0; j < 32; ++j) {
    int c = g * 32 + j;
    ob[(size_t)c * HW] = vals[j] * inv * w[c];
  }
}

// ---------------- conv1x1 GEMM body: BM=64 outs x BN=32 px, BK=128, 256 thr ----------------
template <int GELU, int RES>
__device__ __forceinline__ void conv_body(
    const float* __restrict__ Xb, const float* __restrict__ W,
    const float* __restrict__ bias, const float* __restrict__ resb,
    float* __restrict__ outb, int Cin, int p0, int o0) {
  __shared__ __align__(16) float sW[64][132];   // [o][k], 132 keeps rows 16B-aligned
  __shared__ __align__(16) float sX[128][36];   // [k][p]
  int t  = threadIdx.x;
  int tx = t & 7;    // 8 pixel groups x 4 px
  int ty = t >> 3;   // 32 out groups x 2 outs (ty, ty+32)
  float acc[2][4] = {{0.f}};
  for (int kb = 0; kb < Cin; kb += 128) {
#pragma unroll
    for (int i = 0; i < 8; ++i) {               // 64x128 = 2048 float4
      int idx = t + i * 256;
      int oo = idx >> 5, c4 = (idx & 31) * 4;
      float4 v = *(const float4*)&W[(size_t)(o0 + oo) * Cin + kb + c4];
      *(float4*)&sW[oo][c4] = v;
    }
#pragma unroll
    for (int i = 0; i < 4; ++i) {               // 128x32 = 1024 float4
      int idx = t + i * 256;
      int kk = idx >> 3, c4 = (idx & 7) * 4;
      float4 v = *(const float4*)&Xb[(size_t)(kb + kk) * HW + p0 + c4];
      *(float4*)&sX[kk][c4] = v;
    }
    __syncthreads();
#pragma unroll 8
    for (int kk = 0; kk < 128; ++kk) {
      float a0 = sW[ty][kk];
      float a1 = sW[ty + 32][kk];
      float4 bv = *(const float4*)&sX[kk][tx * 4];
      acc[0][0] += a0 * bv.x; acc[0][1] += a0 * bv.y;
      acc[0][2] += a0 * bv.z; acc[0][3] += a0 * bv.w;
      acc[1][0] += a1 * bv.x; acc[1][1] += a1 * bv.y;
      acc[1][2] += a1 * bv.z; acc[1][3] += a1 * bv.w;
    }
    __syncthreads();
  }
#pragma unroll
  for (int m = 0; m < 2; ++m) {
    int o = o0 + ty + m * 32;
    float bv = bias[o];
    float4 r;
    float* dst = &outb[(size_t)o * HW + p0 + tx * 4];
#pragma unroll
    for (int n = 0; n < 4; ++n) {
      float v = acc[m][n] + bv;
      if (GELU) v = 0.5f * v * (1.0f + erff(v * 0.70710678118654752f));
      if (RES)  v += resb[(size_t)o * HW + p0 + tx * 4 + n];
      (&r.x)[n] = v;
    }
    *(float4*)dst = r;
  }
}

template <int GELU, int RES>
__global__ __launch_bounds__(256) void conv1x1_k(
    const float* __restrict__ X, const float* __restrict__ W,
    const float* __restrict__ bias, const float* __restrict__ res,
    float* __restrict__ out, int Cin) {
  int b = blockIdx.z;
  int Cout = gridDim.y * 64;
  conv_body<GELU, RES>(X + (size_t)b * Cin * HW, W, bias,
                       RES ? res + (size_t)b * Cout * HW : nullptr,
                       out + (size_t)b * Cout * HW, Cin,
                       blockIdx.x * 32, blockIdx.y * 64);
}

// fused q/k/v projections: blockIdx.z = sel*2 + b, sel 0=q(ZN) 1=k(HN) 2=v(HN)
__global__ __launch_bounds__(256) void qkv_k(
    const float* __restrict__ ZN, const float* __restrict__ HN,
    const float* __restrict__ wq, const float* __restrict__ bq,
    const float* __restrict__ wk, const float* __restrict__ bk,
    const float* __restrict__ wv, const float* __restrict__ bv,
    float* __restrict__ Qb, float* __restrict__ Kb, float* __restrict__ Vb) {
  int z = blockIdx.z;
  int b = z & 1, sel = z >> 1;
  const float* X = (sel == 0 ? ZN : HN) + (size_t)b * CDIM * HW;
  const float* W = sel == 0 ? wq : (sel == 1 ? wk : wv);
  const float* bi = sel == 0 ? bq : (sel == 1 ? bk : bv);
  float* out = (sel == 0 ? Qb : (sel == 1 ? Kb : Vb)) + (size_t)b * CDIM * HW;
  conv_body<0, 0>(X, W, bi, nullptr, out, CDIM, blockIdx.x * 32, blockIdx.y * 64);
}

// ---------------- neighborhood attention v2: block 256 = 64 x * 4 d-slices ----------------
// grid (H, HEADS, B). Each (x,dg) thread: ~12 full-dot scores, then softmax+PV on 8 d's.
__global__ __launch_bounds__(256) void nattn(
    const float* __restrict__ Q, const float* __restrict__ K,
    const float* __restrict__ V, float* __restrict__ O) {
  __shared__ float sS[49][64];
  const int t  = threadIdx.x;
  const int x  = t & 63;
  const int dg = t >> 6;          // 0..3, owns d in [dg*8, dg*8+8)
  const int y  = blockIdx.x;
  const int h  = blockIdx.y;
  const int b  = blockIdx.z;
  const size_t base = (size_t)(b * CDIM + h * HD) * HW;
  const float scale = 0.17677669529663687f;  // 32^-0.5

  const float* Qp = Q + base + y * 64 + x;
  float q[HD];
#pragma unroll
  for (int d = 0; d < HD; ++d) q[d] = Qp[(size_t)d * HW];

  // neighbors split 13/12/12/12 across the 4 waves
  int nb_start = (dg == 0) ? 0 : dg * 12 + 1;
  int nb_end   = (dg == 0) ? 13 : nb_start + 12;
  for (int nb = nb_start; nb < nb_end; ++nb) {
    int dy = nb / 7 - 3, dx = nb % 7 - 3;
    int ny = y + dy, nx = x + dx;
    int nyc = min(max(ny, 0), 63), nxc = min(max(nx, 0), 63);
    bool valid = (ny == nyc) && (nx == nxc);
    const float* Kp = K + base + nyc * 64 + nxc;
    float acc = 0.f;
#pragma unroll
    for (int d = 0; d < HD; ++d) acc += q[d] * Kp[(size_t)d * HW];
    sS[nb][x] = valid ? acc * scale : -1e30f;
  }
  __syncthreads();

  float m = -1e30f;
#pragma unroll
  for (int nb = 0; nb < 49; ++nb) m = fmaxf(m, sS[nb][x]);
  float sum = 0.f;
  float o[8];
#pragma unroll
  for (int j = 0; j < 8; ++j) o[j] = 0.f;
  for (int dy = -3; dy <= 3; ++dy) {
    int nyc = min(max(y + dy, 0), 63);
    for (int dx = -3; dx <= 3; ++dx) {
      int nxc = min(max(x + dx, 0), 63);
      float p = __expf(sS[(dy + 3) * 7 + (dx + 3)][x] - m);  // invalid -> 0
      sum += p;
      const float* Vp = V + base + nyc * 64 + nxc + (size_t)(dg * 8) * HW;
#pragma unroll
      for (int j = 0; j < 8; ++j) o[j] += p * Vp[(size_t)j * HW];
    }
  }
  float inv = 1.0f / sum;
  float* Op = O + base + (size_t)(dg * 8) * HW + y * 64 + x;
#pragma unroll
  for (int j = 0; j < 8; ++j) Op[(size_t)j * HW] = o[j] * inv;
}

// ---------------- launch ----------------
extern "C" void kernel_launch(void* const* d_in, const int* in_sizes, int n_in,
                              void* d_out, int out_size, void* d_ws, size_t ws_size,
                              hipStream_t stream) {
  const float* z   = (const float*)d_in[0];
  const float* h   = (const float*)d_in[1];
  const float* wzn = (const float*)d_in[2];
  const float* whn = (const float*)d_in[3];
  const float* wq  = (const float*)d_in[4];
  const float* bq  = (const float*)d_in[5];
  const float* wk  = (const float*)d_in[6];
  const float* bk  = (const float*)d_in[7];
  const float* wv  = (const float*)d_in[8];
  const float* bv  = (const float*)d_in[9];
  const float* wo  = (const float*)d_in[10];
  const float* bo  = (const float*)d_in[11];
  const float* wfn = (const float*)d_in[12];
  const float* w1  = (const float*)d_in[13];
  const float* b1  = (const float*)d_in[14];
  const float* w2  = (const float*)d_in[15];
  const float* b2  = (const float*)d_in[16];
  float* out = (float*)d_out;
  float* ws  = (float*)d_ws;

  const size_t SLAB = 2u * 1024u * 1024u;  // 2M floats = 8MB
  float* ZN   = ws;
  float* HN   = ws + 1 * SLAB;
  float* Qb   = ws + 2 * SLAB;
  float* Kb   = ws + 3 * SLAB;
  float* Vb   = ws + 4 * SLAB;
  float* ZNEW = ws + 5 * SLAB;
  float* ATT  = ZN;
  float* FN   = HN;
  float* HID  = Qb;   // [B][256][HW] spans Qb..Kb

  rmsnorm2<<<dim3(128, 2), 256, 0, stream>>>(z, wzn, ZN, h, whn, HN);
  qkv_k<<<dim3(128, 2, 6), 256, 0, stream>>>(ZN, HN, wq, bq, wk, bk, wv, bv, Qb, Kb, Vb);
  nattn<<<dim3(64, HEADS, 2), 256, 0, stream>>>(Qb, Kb, Vb, ATT);
  conv1x1_k<0, 1><<<dim3(128, 2, 2), 256, 0, stream>>>(ATT, wo, bo, z, ZNEW, 128);
  rmsnorm2<<<dim3(128, 1), 256, 0, stream>>>(ZNEW, wfn, FN, ZNEW, wfn, FN);
  conv1x1_k<1, 0><<<dim3(128, 4, 2), 256, 0, stream>>>(FN, w1, b1, nullptr, HID, 128);
  conv1x1_k<0, 1><<<dim3(128, 2, 2), 256, 0, stream>>>(HID, w2, b2, ZNEW, out, 256);
}

// Round 3
// 74.702 us; speedup vs baseline: 4.5430x; 1.4745x over previous
//
#include <hip/hip_runtime.h>
#include <math.h>

#define CDIM 128
#define HW   4096
#define HEADS 4
#define HD   32

// ---------------- RMSNorm (channel axis), two tensors via blockIdx.y ----------------
__global__ __launch_bounds__(256) void rmsnorm2(
    const float* __restrict__ x0, const float* __restrict__ w0, float* __restrict__ o0,
    const float* __restrict__ x1, const float* __restrict__ w1, float* __restrict__ o1) {
  const float* x; const float* w; float* o;
  if (blockIdx.y == 0) { x = x0; w = w0; o = o0; }
  else                 { x = x1; w = w1; o = o1; }
  int t  = threadIdx.x;
  int pl = t & 63;
  int g  = t >> 6;
  int gp = blockIdx.x * 64 + pl;
  size_t base = (size_t)(gp >> 12) * CDIM * HW + (gp & 4095);
  const float* xb = x + base;
  float*       ob = o + base;
  float vals[32];
  float ss = 0.f;
#pragma unroll
  for (int j = 0; j < 32; ++j) {
    float v = xb[(size_t)(g * 32 + j) * HW];
    vals[j] = v;
    ss += v * v;
  }
  __shared__ float sh[4][64];
  sh[g][pl] = ss;
  __syncthreads();
  float tot = sh[0][pl] + sh[1][pl] + sh[2][pl] + sh[3][pl];
  float inv = rsqrtf(tot * (1.0f / CDIM) + 1e-8f);
#pragma unroll
  for (int j = 0; j < 32; ++j) {
    int c = g * 32 + j;
    ob[(size_t)c * HW] = vals[j] * inv * w[c];
  }
}

// ---------------- conv1x1 GEMM body: BM=64 outs x BN=32 px, BK=128, 256 thr ----------------
template <int GELU, int RES>
__device__ __forceinline__ void conv_body(
    const float* __restrict__ Xb, const float* __restrict__ W,
    const float* __restrict__ bias, const float* __restrict__ resb,
    float* __restrict__ outb, int Cin, int p0, int o0) {
  __shared__ __align__(16) float sW[64][132];   // [o][k], rows 16B-aligned
  __shared__ __align__(16) float sX[128][36];   // [k][p]
  int t  = threadIdx.x;
  int tx = t & 7;    // 8 pixel groups x 4 px
  int ty = t >> 3;   // 32 out groups x 2 outs (ty, ty+32)
  float acc[2][4] = {{0.f}};
  for (int kb = 0; kb < Cin; kb += 128) {
#pragma unroll
    for (int i = 0; i < 8; ++i) {               // 64x128 = 2048 float4
      int idx = t + i * 256;
      int oo = idx >> 5, c4 = (idx & 31) * 4;
      float4 v = *(const float4*)&W[(size_t)(o0 + oo) * Cin + kb + c4];
      *(float4*)&sW[oo][c4] = v;
    }
#pragma unroll
    for (int i = 0; i < 4; ++i) {               // 128x32 = 1024 float4
      int idx = t + i * 256;
      int kk = idx >> 3, c4 = (idx & 7) * 4;
      float4 v = *(const float4*)&Xb[(size_t)(kb + kk) * HW + p0 + c4];
      *(float4*)&sX[kk][c4] = v;
    }
    __syncthreads();
#pragma unroll 8
    for (int kk = 0; kk < 128; ++kk) {
      float a0 = sW[ty][kk];
      float a1 = sW[ty + 32][kk];
      float4 bv = *(const float4*)&sX[kk][tx * 4];
      acc[0][0] += a0 * bv.x; acc[0][1] += a0 * bv.y;
      acc[0][2] += a0 * bv.z; acc[0][3] += a0 * bv.w;
      acc[1][0] += a1 * bv.x; acc[1][1] += a1 * bv.y;
      acc[1][2] += a1 * bv.z; acc[1][3] += a1 * bv.w;
    }
    __syncthreads();
  }
#pragma unroll
  for (int m = 0; m < 2; ++m) {
    int o = o0 + ty + m * 32;
    float bv = bias[o];
    float4 r;
    float* dst = &outb[(size_t)o * HW + p0 + tx * 4];
#pragma unroll
    for (int n = 0; n < 4; ++n) {
      float v = acc[m][n] + bv;
      if (GELU) v = 0.5f * v * (1.0f + erff(v * 0.70710678118654752f));
      if (RES)  v += resb[(size_t)o * HW + p0 + tx * 4 + n];
      (&r.x)[n] = v;
    }
    *(float4*)dst = r;
  }
}

template <int GELU, int RES>
__global__ __launch_bounds__(256) void conv1x1_k(
    const float* __restrict__ X, const float* __restrict__ W,
    const float* __restrict__ bias, const float* __restrict__ res,
    float* __restrict__ out, int Cin) {
  int b = blockIdx.z;
  int Cout = gridDim.y * 64;
  conv_body<GELU, RES>(X + (size_t)b * Cin * HW, W, bias,
                       RES ? res + (size_t)b * Cout * HW : nullptr,
                       out + (size_t)b * Cout * HW, Cin,
                       blockIdx.x * 32, blockIdx.y * 64);
}

// fused q/k/v projections: blockIdx.z = sel*2 + b, sel 0=q(ZN) 1=k(HN) 2=v(HN)
__global__ __launch_bounds__(256) void qkv_k(
    const float* __restrict__ ZN, const float* __restrict__ HN,
    const float* __restrict__ wq, const float* __restrict__ bq,
    const float* __restrict__ wk, const float* __restrict__ bk,
    const float* __restrict__ wv, const float* __restrict__ bv,
    float* __restrict__ Qb, float* __restrict__ Kb, float* __restrict__ Vb) {
  int z = blockIdx.z;
  int b = z & 1, sel = z >> 1;
  const float* X = (sel == 0 ? ZN : HN) + (size_t)b * CDIM * HW;
  const float* W = sel == 0 ? wq : (sel == 1 ? wk : wv);
  const float* bi = sel == 0 ? bq : (sel == 1 ? bk : bv);
  float* out = (sel == 0 ? Qb : (sel == 1 ? Kb : Vb)) + (size_t)b * CDIM * HW;
  conv_body<0, 0>(X, W, bi, nullptr, out, CDIM, blockIdx.x * 32, blockIdx.y * 64);
}

// ---------------- neighborhood attention v3: LDS-staged K/V ----------------
// Block = (2 rows, head, batch): 512 threads = 128 px * 4 d-groups.
// LDS 128 KiB: sK[32][8][64] | sV[32][8][64]; score buf sS[49][128] aliases sK.
__global__ __launch_bounds__(512) void nattn(
    const float* __restrict__ Q, const float* __restrict__ K,
    const float* __restrict__ V, float* __restrict__ O) {
  __shared__ float smem[32768];   // 128 KiB
  const int t  = threadIdx.x;
  const int px = t & 127;
  const int x  = px & 63;
  const int r  = px >> 6;
  const int dg = t >> 7;          // 0..3
  const int y0 = blockIdx.x * 2;
  const int h  = blockIdx.y;
  const int b  = blockIdx.z;
  const size_t base = (size_t)(b * CDIM + h * HD) * HW;
  const int ybase = y0 - 3;

  // ---- stage K,V tiles [d][yy][x], yy holds global row clamp(ybase+yy) ----
  {
    const float* Kb = K + base;
    const float* Vb = V + base;
#pragma unroll
    for (int i = 0; i < 8; ++i) {
      int u  = t + i * 512;        // float4 unit 0..4095
      int d  = u >> 7;
      int yy = (u >> 4) & 7;
      int xq = (u & 15) * 4;
      int gy = min(max(ybase + yy, 0), 63);
      float4 kv = *(const float4*)&Kb[(size_t)d * HW + gy * 64 + xq];
      float4 vv = *(const float4*)&Vb[(size_t)d * HW + gy * 64 + xq];
      *(float4*)&smem[d * 512 + yy * 64 + xq]         = kv;
      *(float4*)&smem[16384 + d * 512 + yy * 64 + xq] = vv;
    }
  }
  // q into regs (global, L2-resident, coalesced along x)
  const float* Qp = Q + base + (size_t)(y0 + r) * 64 + x;
  float q[32];
#pragma unroll
  for (int d = 0; d < 32; ++d) q[d] = Qp[(size_t)d * HW];
  __syncthreads();

  // ---- scores: 13/12/12/12 neighbors per d-group, held in regs ----
  const float scale = 0.17677669529663687f;  // 32^-0.5
  const int nb0    = (dg == 0) ? 0 : dg * 12 + 1;
  const int ncount = (dg == 0) ? 13 : 12;
  float sreg[13];
#pragma unroll
  for (int j = 0; j < 13; ++j) {     // static j keeps sreg in registers
    if (j < ncount) {
      int nb = nb0 + j;
      int dy = nb / 7 - 3;
      int dx = nb % 7 - 3;
      int ry = r + dy + 3;           // 0..7 tile row index
      int nx = x + dx;
      int xx = min(max(nx, 0), 63);
      int ny = y0 + r + dy;
      bool valid = (ny >= 0) && (ny <= 63) && (nx >= 0) && (nx <= 63);
      const float* kb = &smem[ry * 64 + xx];
      float acc = 0.f;
#pragma unroll
      for (int d = 0; d < 32; ++d) acc += q[d] * kb[d * 512];
      sreg[j] = valid ? acc * scale : -1e30f;
    }
  }
  __syncthreads();                   // all sK reads complete
#pragma unroll
  for (int j = 0; j < 13; ++j)
    if (j < ncount) smem[(nb0 + j) * 128 + px] = sreg[j];   // sS overlays sK
  __syncthreads();

  // ---- softmax (thread-private) + PV on this thread's 8 d's ----
  float s[49];
#pragma unroll
  for (int nb = 0; nb < 49; ++nb) s[nb] = smem[nb * 128 + px];
  float m = -1e30f;
#pragma unroll
  for (int nb = 0; nb < 49; ++nb) m = fmaxf(m, s[nb]);
  float o[8];
#pragma unroll
  for (int j = 0; j < 8; ++j) o[j] = 0.f;
  float sum = 0.f;
#pragma unroll
  for (int nb = 0; nb < 49; ++nb) {
    float p = __expf(s[nb] - m);     // invalid -> exp(-huge) = 0
    sum += p;
    int ry = r + nb / 7;             // nb static: compile-time div/mod
    int xx = min(max(x + nb % 7 - 3, 0), 63);
    const float* vb = &smem[16384 + dg * 4096 + ry * 64 + xx];
#pragma unroll
    for (int j = 0; j < 8; ++j) o[j] += p * vb[j * 512];
  }
  float inv = 1.0f / sum;
  float* Op = O + base + (size_t)(dg * 8) * HW + (size_t)(y0 + r) * 64 + x;
#pragma unroll
  for (int j = 0; j < 8; ++j) Op[(size_t)j * HW] = o[j] * inv;
}

// ---------------- launch ----------------
extern "C" void kernel_launch(void* const* d_in, const int* in_sizes, int n_in,
                              void* d_out, int out_size, void* d_ws, size_t ws_size,
                              hipStream_t stream) {
  const float* z   = (const float*)d_in[0];
  const float* h   = (const float*)d_in[1];
  const float* wzn = (const float*)d_in[2];
  const float* whn = (const float*)d_in[3];
  const float* wq  = (const float*)d_in[4];
  const float* bq  = (const float*)d_in[5];
  const float* wk  = (const float*)d_in[6];
  const float* bk  = (const float*)d_in[7];
  const float* wv  = (const float*)d_in[8];
  const float* bv  = (const float*)d_in[9];
  const float* wo  = (const float*)d_in[10];
  const float* bo  = (const float*)d_in[11];
  const float* wfn = (const float*)d_in[12];
  const float* w1  = (const float*)d_in[13];
  const float* b1  = (const float*)d_in[14];
  const float* w2  = (const float*)d_in[15];
  const float* b2  = (const float*)d_in[16];
  float* out = (float*)d_out;
  float* ws  = (float*)d_ws;

  const size_t SLAB = 2u * 1024u * 1024u;  // 2M floats = 8MB
  float* ZN   = ws;
  float* HN   = ws + 1 * SLAB;
  float* Qb   = ws + 2 * SLAB;
  float* Kb   = ws + 3 * SLAB;
  float* Vb   = ws + 4 * SLAB;
  float* ZNEW = ws + 5 * SLAB;
  float* ATT  = ZN;
  float* FN   = HN;
  float* HID  = Qb;   // [B][256][HW] spans Qb..Kb

  rmsnorm2<<<dim3(128, 2), 256, 0, stream>>>(z, wzn, ZN, h, whn, HN);
  qkv_k<<<dim3(128, 2, 6), 256, 0, stream>>>(ZN, HN, wq, bq, wk, bk, wv, bv, Qb, Kb, Vb);
  nattn<<<dim3(32, HEADS, 2), 512, 0, stream>>>(Qb, Kb, Vb, ATT);
  conv1x1_k<0, 1><<<dim3(128, 2, 2), 256, 0, stream>>>(ATT, wo, bo, z, ZNEW, 128);
  rmsnorm2<<<dim3(128, 1), 256, 0, stream>>>(ZNEW, wfn, FN, ZNEW, wfn, FN);
  conv1x1_k<1, 0><<<dim3(128, 4, 2), 256, 0, stream>>>(FN, w1, b1, nullptr, HID, 128);
  conv1x1_k<0, 1><<<dim3(128, 2, 2), 256, 0, stream>>>(HID, w2, b2, ZNEW, out, 256);
}

// Round 4
// 64.198 us; speedup vs baseline: 5.2863x; 1.1636x over previous
//
#include <hip/hip_runtime.h>
#include <math.h>

#define CDIM 128
#define HW   4096
#define HEADS 4
#define HD   32

typedef __attribute__((ext_vector_type(8))) short bf16x8;
typedef __attribute__((ext_vector_type(4))) float f32x4;

static __device__ __forceinline__ unsigned int f2bf(float f) {
  union { float f; unsigned int u; } v; v.f = f;
  unsigned int r = v.u + 0x7FFF + ((v.u >> 16) & 1);   // RNE
  return r >> 16;
}

// ---------------- weight fp32 -> bf16 prep (all 6 matrices into WB) ----------------
// WB ushort offsets: wq 0, wk 16384, wv 32768, wo 49152, w1 65536, w2 98304. Total 131072.
__global__ __launch_bounds__(256) void wcvt(
    const float* __restrict__ wq, const float* __restrict__ wk,
    const float* __restrict__ wv, const float* __restrict__ wo,
    const float* __restrict__ w1, const float* __restrict__ w2,
    ushort* __restrict__ WB) {
  int e = (blockIdx.x * 256 + threadIdx.x) * 4;   // grid 128 -> e < 131072
  const float* src; int off;
  if      (e < 16384) { src = wq; off = 0; }
  else if (e < 32768) { src = wk; off = 16384; }
  else if (e < 49152) { src = wv; off = 32768; }
  else if (e < 65536) { src = wo; off = 49152; }
  else if (e < 98304) { src = w1; off = 65536; }
  else                { src = w2; off = 98304; }
  float4 v = *(const float4*)&src[e - off];
  uint2 r;
  r.x = f2bf(v.x) | (f2bf(v.y) << 16);
  r.y = f2bf(v.z) | (f2bf(v.w) << 16);
  *(uint2*)&WB[e] = r;
}

// ---------------- RMSNorm (channel axis): fp32 NCHW in -> bf16 [p][c] out ----------------
__global__ __launch_bounds__(256) void rmsnorm2(
    const float* __restrict__ x0, const float* __restrict__ w0, ushort* __restrict__ o0,
    const float* __restrict__ x1, const float* __restrict__ w1, ushort* __restrict__ o1) {
  const float* x; const float* w; ushort* o;
  if (blockIdx.y == 0) { x = x0; w = w0; o = o0; }
  else                 { x = x1; w = w1; o = o1; }
  int t  = threadIdx.x;
  int pl = t & 63;
  int g  = t >> 6;
  int gp = blockIdx.x * 64 + pl;          // global pixel P (b*4096 + p)
  size_t base = (size_t)(gp >> 12) * CDIM * HW + (gp & 4095);
  const float* xb = x + base;
  float vals[32];
  float ss = 0.f;
#pragma unroll
  for (int j = 0; j < 32; ++j) {
    float v = xb[(size_t)(g * 32 + j) * HW];
    vals[j] = v;
    ss += v * v;
  }
  __shared__ float sh[4][64];
  sh[g][pl] = ss;
  __syncthreads();
  float tot = sh[0][pl] + sh[1][pl] + sh[2][pl] + sh[3][pl];
  float inv = rsqrtf(tot * (1.0f / CDIM) + 1e-8f);
  unsigned int pk[16];
#pragma unroll
  for (int j = 0; j < 16; ++j) {
    float a = vals[2 * j]     * inv * w[g * 32 + 2 * j];
    float b = vals[2 * j + 1] * inv * w[g * 32 + 2 * j + 1];
    pk[j] = f2bf(a) | (f2bf(b) << 16);
  }
  unsigned int* dst = (unsigned int*)&o[(size_t)gp * CDIM + g * 32];
#pragma unroll
  for (int q = 0; q < 4; ++q)
    *(uint4*)(dst + q * 4) = make_uint4(pk[q*4], pk[q*4+1], pk[q*4+2], pk[q*4+3]);
}

// ---------------- MFMA conv1x1: X[P][CIN] bf16 x W[Cout][CIN] bf16 ----------------
// Block 256 = 4 waves (2M x 2N). Wave tile 32 Cout x 64 px. No LDS; frags direct from L1/L2.
// A-frag lane l: W[m0+lr][k0+lk*8..+8]; B-frag: X[p0+lr][k0+lk*8..+8]; D: row=lk*4+j, col=lr.
template <int CIN, int GELU, int RES, int OUTB>
__device__ __forceinline__ void mm_body(
    const ushort* __restrict__ X, const ushort* __restrict__ Wb,
    const float* __restrict__ bias, const float* __restrict__ res,
    float* __restrict__ outF, ushort* __restrict__ outB,
    int Cout, int pblk, int mblk) {
  const int t  = threadIdx.x;
  const int w  = t >> 6;
  const int wm = w & 1, wn = w >> 1;
  const int l  = t & 63;
  const int lr = l & 15, lk = l >> 4;
  const int m0 = mblk + wm * 32;
  const int p0 = pblk + wn * 64;

  const ushort* A0 = Wb + (size_t)(m0 + lr) * CIN + lk * 8;
  const ushort* A1 = A0 + 16 * CIN;
  const ushort* B0 = X + (size_t)(p0 + lr) * CIN + lk * 8;
  const ushort* B1 = B0 + 16 * CIN;
  const ushort* B2 = B0 + 32 * CIN;
  const ushort* B3 = B0 + 48 * CIN;

  f32x4 acc[2][4] = {};
#pragma unroll
  for (int k0 = 0; k0 < CIN; k0 += 32) {
    bf16x8 a0 = *(const bf16x8*)(A0 + k0);
    bf16x8 a1 = *(const bf16x8*)(A1 + k0);
    bf16x8 b0 = *(const bf16x8*)(B0 + k0);
    bf16x8 b1 = *(const bf16x8*)(B1 + k0);
    bf16x8 b2 = *(const bf16x8*)(B2 + k0);
    bf16x8 b3 = *(const bf16x8*)(B3 + k0);
    acc[0][0] = __builtin_amdgcn_mfma_f32_16x16x32_bf16(a0, b0, acc[0][0], 0, 0, 0);
    acc[0][1] = __builtin_amdgcn_mfma_f32_16x16x32_bf16(a0, b1, acc[0][1], 0, 0, 0);
    acc[0][2] = __builtin_amdgcn_mfma_f32_16x16x32_bf16(a0, b2, acc[0][2], 0, 0, 0);
    acc[0][3] = __builtin_amdgcn_mfma_f32_16x16x32_bf16(a0, b3, acc[0][3], 0, 0, 0);
    acc[1][0] = __builtin_amdgcn_mfma_f32_16x16x32_bf16(a1, b0, acc[1][0], 0, 0, 0);
    acc[1][1] = __builtin_amdgcn_mfma_f32_16x16x32_bf16(a1, b1, acc[1][1], 0, 0, 0);
    acc[1][2] = __builtin_amdgcn_mfma_f32_16x16x32_bf16(a1, b2, acc[1][2], 0, 0, 0);
    acc[1][3] = __builtin_amdgcn_mfma_f32_16x16x32_bf16(a1, b3, acc[1][3], 0, 0, 0);
  }

#pragma unroll
  for (int mf = 0; mf < 2; ++mf) {
    int obase = m0 + mf * 16 + lk * 4;
    f32x4 bv = *(const f32x4*)&bias[obase];
#pragma unroll
    for (int nf = 0; nf < 4; ++nf) {
      int P = p0 + nf * 16 + lr;
      float r[4];
#pragma unroll
      for (int j = 0; j < 4; ++j) {
        float v = acc[mf][nf][j] + bv[j];
        if (GELU) v = 0.5f * v * (1.0f + erff(v * 0.70710678118654752f));
        r[j] = v;
      }
      if (OUTB) {
        uint2 pk;
        pk.x = f2bf(r[0]) | (f2bf(r[1]) << 16);
        pk.y = f2bf(r[2]) | (f2bf(r[3]) << 16);
        *(uint2*)&outB[(size_t)P * Cout + obase] = pk;
      } else {
        int b = P >> 12, p = P & 4095;
        size_t base = ((size_t)(b * Cout + obase)) * HW + p;
#pragma unroll
        for (int j = 0; j < 4; ++j) {
          float v = r[j];
          if (RES) v += res[base + (size_t)j * HW];
          outF[base + (size_t)j * HW] = v;
        }
      }
    }
  }
}

// fused q/k/v: grid (64, 2, 3); sel 0=q(ZN) 1=k(HN) 2=v(HN); fp32 [c][p] outputs
__global__ __launch_bounds__(256) void qkv_mm(
    const ushort* __restrict__ ZN, const ushort* __restrict__ HN,
    const ushort* __restrict__ WB,
    const float* __restrict__ bq, const float* __restrict__ bk, const float* __restrict__ bv,
    float* __restrict__ Qf, float* __restrict__ Kf, float* __restrict__ Vf) {
  int sel = blockIdx.z;
  const ushort* X = (sel == 0) ? ZN : HN;
  const ushort* W = WB + sel * 16384;
  const float* bias = (sel == 0) ? bq : (sel == 1 ? bk : bv);
  float* out = (sel == 0) ? Qf : (sel == 1 ? Kf : Vf);
  mm_body<128, 0, 0, 0>(X, W, bias, nullptr, out, nullptr, 128,
                        blockIdx.x * 128, blockIdx.y * 64);
}

template <int CIN, int GELU, int RES, int OUTB>
__global__ __launch_bounds__(256) void convmm(
    const ushort* __restrict__ X, const ushort* __restrict__ W,
    const float* __restrict__ bias, const float* __restrict__ res,
    float* __restrict__ outF, ushort* __restrict__ outB, int Cout) {
  mm_body<CIN, GELU, RES, OUTB>(X, W, bias, res, outF, outB, Cout,
                                blockIdx.x * 128, blockIdx.y * 64);
}

// ---------------- neighborhood attention (LDS-staged K/V), bf16 [p][c] output ----------------
__global__ __launch_bounds__(512) void nattn(
    const float* __restrict__ Q, const float* __restrict__ K,
    const float* __restrict__ V, ushort* __restrict__ ATT) {
  __shared__ float smem[32768];   // 128 KiB
  const int t  = threadIdx.x;
  const int px = t & 127;
  const int x  = px & 63;
  const int r  = px >> 6;
  const int dg = t >> 7;          // 0..3
  const int y0 = blockIdx.x * 2;
  const int h  = blockIdx.y;
  const int b  = blockIdx.z;
  const size_t base = (size_t)(b * CDIM + h * HD) * HW;
  const int ybase = y0 - 3;

  {
    const float* Kb = K + base;
    const float* Vb = V + base;
#pragma unroll
    for (int i = 0; i < 8; ++i) {
      int u  = t + i * 512;
      int d  = u >> 7;
      int yy = (u >> 4) & 7;
      int xq = (u & 15) * 4;
      int gy = min(max(ybase + yy, 0), 63);
      float4 kv = *(const float4*)&Kb[(size_t)d * HW + gy * 64 + xq];
      float4 vv = *(const float4*)&Vb[(size_t)d * HW + gy * 64 + xq];
      *(float4*)&smem[d * 512 + yy * 64 + xq]         = kv;
      *(float4*)&smem[16384 + d * 512 + yy * 64 + xq] = vv;
    }
  }
  const float* Qp = Q + base + (size_t)(y0 + r) * 64 + x;
  float q[32];
#pragma unroll
  for (int d = 0; d < 32; ++d) q[d] = Qp[(size_t)d * HW];
  __syncthreads();

  const float scale = 0.17677669529663687f;
  const int nb0    = (dg == 0) ? 0 : dg * 12 + 1;
  const int ncount = (dg == 0) ? 13 : 12;
  float sreg[13];
#pragma unroll
  for (int j = 0; j < 13; ++j) {
    if (j < ncount) {
      int nb = nb0 + j;
      int dy = nb / 7 - 3;
      int dx = nb % 7 - 3;
      int ry = r + dy + 3;
      int nx = x + dx;
      int xx = min(max(nx, 0), 63);
      int ny = y0 + r + dy;
      bool valid = (ny >= 0) && (ny <= 63) && (nx >= 0) && (nx <= 63);
      const float* kb = &smem[ry * 64 + xx];
      float acc = 0.f;
#pragma unroll
      for (int d = 0; d < 32; ++d) acc += q[d] * kb[d * 512];
      sreg[j] = valid ? acc * scale : -1e30f;
    }
  }
  __syncthreads();
#pragma unroll
  for (int j = 0; j < 13; ++j)
    if (j < ncount) smem[(nb0 + j) * 128 + px] = sreg[j];
  __syncthreads();

  float s[49];
#pragma unroll
  for (int nb = 0; nb < 49; ++nb) s[nb] = smem[nb * 128 + px];
  float m = -1e30f;
#pragma unroll
  for (int nb = 0; nb < 49; ++nb) m = fmaxf(m, s[nb]);
  float o[8];
#pragma unroll
  for (int j = 0; j < 8; ++j) o[j] = 0.f;
  float sum = 0.f;
#pragma unroll
  for (int nb = 0; nb < 49; ++nb) {
    float p = __expf(s[nb] - m);
    sum += p;
    int ry = r + nb / 7;
    int xx = min(max(x + nb % 7 - 3, 0), 63);
    const float* vb = &smem[16384 + dg * 4096 + ry * 64 + xx];
#pragma unroll
    for (int j = 0; j < 8; ++j) o[j] += p * vb[j * 512];
  }
  float inv = 1.0f / sum;
  int P = b * HW + (y0 + r) * 64 + x;
  unsigned int pk[4];
#pragma unroll
  for (int j = 0; j < 4; ++j)
    pk[j] = f2bf(o[2 * j] * inv) | (f2bf(o[2 * j + 1] * inv) << 16);
  *(uint4*)&ATT[(size_t)P * CDIM + h * HD + dg * 8] = make_uint4(pk[0], pk[1], pk[2], pk[3]);
}

// ---------------- launch ----------------
extern "C" void kernel_launch(void* const* d_in, const int* in_sizes, int n_in,
                              void* d_out, int out_size, void* d_ws, size_t ws_size,
                              hipStream_t stream) {
  const float* z   = (const float*)d_in[0];
  const float* h   = (const float*)d_in[1];
  const float* wzn = (const float*)d_in[2];
  const float* whn = (const float*)d_in[3];
  const float* wq  = (const float*)d_in[4];
  const float* bq  = (const float*)d_in[5];
  const float* wk  = (const float*)d_in[6];
  const float* bk  = (const float*)d_in[7];
  const float* wv  = (const float*)d_in[8];
  const float* bv  = (const float*)d_in[9];
  const float* wo  = (const float*)d_in[10];
  const float* bo  = (const float*)d_in[11];
  const float* wfn = (const float*)d_in[12];
  const float* w1  = (const float*)d_in[13];
  const float* b1  = (const float*)d_in[14];
  const float* w2  = (const float*)d_in[15];
  const float* b2  = (const float*)d_in[16];
  float* out = (float*)d_out;
  float* ws  = (float*)d_ws;

  const size_t SL = 2097152;                 // 2M floats = one fp32 [2][128][4096] tensor
  float*  Qf   = ws;                         // 0..2M
  float*  Kf   = ws + 2 * SL;                // wait: Qf spans 2M floats
  // -- explicit float offsets --
  Qf           = ws + 0 * SL;                // 2M floats
  Kf           = ws + 1 * SL;
  float*  Vf   = ws + 2 * SL;
  float*  ZNEW = ws + 3 * SL;
  ushort* ZN   = (ushort*)(ws + 4 * SL);                  // 1M bf16 (0.5M floats)
  ushort* HN   = (ushort*)(ws + 4 * SL + SL / 4);
  ushort* ATT  = (ushort*)(ws + 4 * SL + 2 * (SL / 4));
  ushort* FN   = (ushort*)(ws + 4 * SL + 3 * (SL / 4));
  ushort* HID  = (ushort*)(ws + 5 * SL);                  // 2M bf16 (1M floats)
  ushort* WB   = (ushort*)(ws + 5 * SL + SL / 2);         // 131072 bf16

  wcvt<<<dim3(128), 256, 0, stream>>>(wq, wk, wv, wo, w1, w2, WB);
  rmsnorm2<<<dim3(128, 2), 256, 0, stream>>>(z, wzn, ZN, h, whn, HN);
  qkv_mm<<<dim3(64, 2, 3), 256, 0, stream>>>(ZN, HN, WB, bq, bk, bv, Qf, Kf, Vf);
  nattn<<<dim3(32, HEADS, 2), 512, 0, stream>>>(Qf, Kf, Vf, ATT);
  convmm<128, 0, 1, 0><<<dim3(64, 2), 256, 0, stream>>>(ATT, WB + 49152, bo, z, ZNEW, nullptr, 128);
  rmsnorm2<<<dim3(128, 1), 256, 0, stream>>>(ZNEW, wfn, FN, ZNEW, wfn, FN);
  convmm<128, 1, 0, 1><<<dim3(64, 4), 256, 0, stream>>>(FN, WB + 65536, b1, nullptr, nullptr, HID, 256);
  convmm<256, 0, 1, 0><<<dim3(64, 2), 256, 0, stream>>>(HID, WB + 98304, b2, ZNEW, out, nullptr, 128);
}

// Round 5
// 50.878 us; speedup vs baseline: 6.6702x; 1.2618x over previous
//
#include <hip/hip_runtime.h>
#include <math.h>

#define CDIM 128
#define HW   4096
#define HEADS 4
#define HD   32

typedef __attribute__((ext_vector_type(8))) short bf16x8;
typedef __attribute__((ext_vector_type(4))) float f32x4;

static __device__ __forceinline__ unsigned int f2bf(float f) {
  union { float f; unsigned int u; } v; v.f = f;
  unsigned int r = v.u + 0x7FFF + ((v.u >> 16) & 1);   // RNE
  return r >> 16;
}
static __device__ __forceinline__ float gelu_f(float v) {
  return 0.5f * v * (1.0f + erff(v * 0.70710678118654752f));
}

// ---------------- prep: wcvt (blocks 0..127) + rmsnorm z (128..255) + rmsnorm h (256..383) ----
// WB ushort offsets: wq 0, wk 16384, wv 32768, wo 49152, w1 65536, w2 98304.
__global__ __launch_bounds__(256) void prep(
    const float* __restrict__ wq, const float* __restrict__ wk,
    const float* __restrict__ wv, const float* __restrict__ wo,
    const float* __restrict__ w1, const float* __restrict__ w2,
    ushort* __restrict__ WB,
    const float* __restrict__ z, const float* __restrict__ wzn, ushort* __restrict__ ZN,
    const float* __restrict__ h, const float* __restrict__ whn, ushort* __restrict__ HN) {
  __shared__ float sh[4][64];
  const int bx = blockIdx.x, t = threadIdx.x;
  if (bx < 128) {
    int e = (bx * 256 + t) * 4;
    const float* src; int off;
    if      (e < 16384) { src = wq; off = 0; }
    else if (e < 32768) { src = wk; off = 16384; }
    else if (e < 49152) { src = wv; off = 32768; }
    else if (e < 65536) { src = wo; off = 49152; }
    else if (e < 98304) { src = w1; off = 65536; }
    else                { src = w2; off = 98304; }
    float4 v = *(const float4*)&src[e - off];
    uint2 r;
    r.x = f2bf(v.x) | (f2bf(v.y) << 16);
    r.y = f2bf(v.z) | (f2bf(v.w) << 16);
    *(uint2*)&WB[e] = r;
    return;
  }
  int gblk = bx - 128;
  const float* x; const float* w; ushort* o;
  if (gblk < 128) { x = z; w = wzn; o = ZN; }
  else            { x = h; w = whn; o = HN; gblk -= 128; }
  int pl = t & 63;
  int g  = t >> 6;
  int gp = gblk * 64 + pl;                // global pixel (b*4096 + p)
  size_t base = (size_t)(gp >> 12) * CDIM * HW + (gp & 4095);
  const float* xb = x + base;
  float vals[32];
  float ss = 0.f;
#pragma unroll
  for (int j = 0; j < 32; ++j) {
    float v = xb[(size_t)(g * 32 + j) * HW];
    vals[j] = v;
    ss += v * v;
  }
  sh[g][pl] = ss;
  __syncthreads();
  float tot = sh[0][pl] + sh[1][pl] + sh[2][pl] + sh[3][pl];
  float inv = rsqrtf(tot * (1.0f / CDIM) + 1e-8f);
  unsigned int pk[16];
#pragma unroll
  for (int j = 0; j < 16; ++j) {
    float a = vals[2 * j]     * inv * w[g * 32 + 2 * j];
    float b = vals[2 * j + 1] * inv * w[g * 32 + 2 * j + 1];
    pk[j] = f2bf(a) | (f2bf(b) << 16);
  }
  unsigned int* dst = (unsigned int*)&o[(size_t)gp * CDIM + g * 32];
#pragma unroll
  for (int q = 0; q < 4; ++q)
    *(uint4*)(dst + q * 4) = make_uint4(pk[q*4], pk[q*4+1], pk[q*4+2], pk[q*4+3]);
}

// ---------------- MFMA conv body (qkv): wave tile 32 Cout x 64 px, block 2M x 2N ----------------
__device__ __forceinline__ void mm_body_qkv(
    const ushort* __restrict__ X, const ushort* __restrict__ Wb,
    const float* __restrict__ bias, float* __restrict__ outF,
    int pblk, int mblk) {
  const int t  = threadIdx.x;
  const int w  = t >> 6;
  const int wm = w & 1, wn = w >> 1;
  const int l  = t & 63;
  const int lr = l & 15, lk = l >> 4;
  const int m0 = mblk + wm * 32;
  const int p0 = pblk + wn * 64;

  const ushort* A0 = Wb + (size_t)(m0 + lr) * 128 + lk * 8;
  const ushort* A1 = A0 + 16 * 128;
  const ushort* B0 = X + (size_t)(p0 + lr) * 128 + lk * 8;

  f32x4 acc[2][4] = {};
#pragma unroll
  for (int k0 = 0; k0 < 128; k0 += 32) {
    bf16x8 a0 = *(const bf16x8*)(A0 + k0);
    bf16x8 a1 = *(const bf16x8*)(A1 + k0);
    bf16x8 b[4];
#pragma unroll
    for (int nf = 0; nf < 4; ++nf) b[nf] = *(const bf16x8*)(B0 + nf * 16 * 128 + k0);
#pragma unroll
    for (int nf = 0; nf < 4; ++nf) {
      acc[0][nf] = __builtin_amdgcn_mfma_f32_16x16x32_bf16(a0, b[nf], acc[0][nf], 0, 0, 0);
      acc[1][nf] = __builtin_amdgcn_mfma_f32_16x16x32_bf16(a1, b[nf], acc[1][nf], 0, 0, 0);
    }
  }
#pragma unroll
  for (int mf = 0; mf < 2; ++mf) {
    int obase = m0 + mf * 16 + lk * 4;
    f32x4 bv = *(const f32x4*)&bias[obase];
#pragma unroll
    for (int nf = 0; nf < 4; ++nf) {
      int P = p0 + nf * 16 + lr;
      int b = P >> 12, p = P & 4095;
      size_t base = ((size_t)(b * CDIM + obase)) * HW + p;
#pragma unroll
      for (int j = 0; j < 4; ++j)
        outF[base + (size_t)j * HW] = acc[mf][nf][j] + bv[j];
    }
  }
}

// fused q/k/v: grid (64, 2, 3); sel 0=q(ZN) 1=k(HN) 2=v(HN); fp32 [c][p] outputs
__global__ __launch_bounds__(256) void qkv_mm(
    const ushort* __restrict__ ZN, const ushort* __restrict__ HN,
    const ushort* __restrict__ WB,
    const float* __restrict__ bq, const float* __restrict__ bk, const float* __restrict__ bv,
    float* __restrict__ Qf, float* __restrict__ Kf, float* __restrict__ Vf) {
  int sel = blockIdx.z;
  const ushort* X = (sel == 0) ? ZN : HN;
  const ushort* W = WB + sel * 16384;
  const float* bias = (sel == 0) ? bq : (sel == 1 ? bk : bv);
  float* out = (sel == 0) ? Qf : (sel == 1 ? Kf : Vf);
  mm_body_qkv(X, W, bias, out, blockIdx.x * 128, blockIdx.y * 64);
}

// ---------------- neighborhood attention (LDS-staged K/V), bf16 [p][c] output ----------------
__global__ __launch_bounds__(512) void nattn(
    const float* __restrict__ Q, const float* __restrict__ K,
    const float* __restrict__ V, ushort* __restrict__ ATT) {
  __shared__ float smem[32768];   // 128 KiB
  const int t  = threadIdx.x;
  const int px = t & 127;
  const int x  = px & 63;
  const int r  = px >> 6;
  const int dg = t >> 7;          // 0..3
  const int y0 = blockIdx.x * 2;
  const int h  = blockIdx.y;
  const int b  = blockIdx.z;
  const size_t base = (size_t)(b * CDIM + h * HD) * HW;
  const int ybase = y0 - 3;

  {
    const float* Kb = K + base;
    const float* Vb = V + base;
#pragma unroll
    for (int i = 0; i < 8; ++i) {
      int u  = t + i * 512;
      int d  = u >> 7;
      int yy = (u >> 4) & 7;
      int xq = (u & 15) * 4;
      int gy = min(max(ybase + yy, 0), 63);
      float4 kv = *(const float4*)&Kb[(size_t)d * HW + gy * 64 + xq];
      float4 vv = *(const float4*)&Vb[(size_t)d * HW + gy * 64 + xq];
      *(float4*)&smem[d * 512 + yy * 64 + xq]         = kv;
      *(float4*)&smem[16384 + d * 512 + yy * 64 + xq] = vv;
    }
  }
  const float* Qp = Q + base + (size_t)(y0 + r) * 64 + x;
  float q[32];
#pragma unroll
  for (int d = 0; d < 32; ++d) q[d] = Qp[(size_t)d * HW];
  __syncthreads();

  const float scale = 0.17677669529663687f;
  const int nb0    = (dg == 0) ? 0 : dg * 12 + 1;
  const int ncount = (dg == 0) ? 13 : 12;
  float sreg[13];
#pragma unroll
  for (int j = 0; j < 13; ++j) {
    if (j < ncount) {
      int nb = nb0 + j;
      int dy = nb / 7 - 3;
      int dx = nb % 7 - 3;
      int ry = r + dy + 3;
      int nx = x + dx;
      int xx = min(max(nx, 0), 63);
      int ny = y0 + r + dy;
      bool valid = (ny >= 0) && (ny <= 63) && (nx >= 0) && (nx <= 63);
      const float* kb = &smem[ry * 64 + xx];
      float acc = 0.f;
#pragma unroll
      for (int d = 0; d < 32; ++d) acc += q[d] * kb[d * 512];
      sreg[j] = valid ? acc * scale : -1e30f;
    }
  }
  __syncthreads();
#pragma unroll
  for (int j = 0; j < 13; ++j)
    if (j < ncount) smem[(nb0 + j) * 128 + px] = sreg[j];
  __syncthreads();

  float s[49];
#pragma unroll
  for (int nb = 0; nb < 49; ++nb) s[nb] = smem[nb * 128 + px];
  float m = -1e30f;
#pragma unroll
  for (int nb = 0; nb < 49; ++nb) m = fmaxf(m, s[nb]);
  float o[8];
#pragma unroll
  for (int j = 0; j < 8; ++j) o[j] = 0.f;
  float sum = 0.f;
#pragma unroll
  for (int nb = 0; nb < 49; ++nb) {
    float p = __expf(s[nb] - m);
    sum += p;
    int ry = r + nb / 7;
    int xx = min(max(x + nb % 7 - 3, 0), 63);
    const float* vb = &smem[16384 + dg * 4096 + ry * 64 + xx];
#pragma unroll
    for (int j = 0; j < 8; ++j) o[j] += p * vb[j * 512];
  }
  float inv = 1.0f / sum;
  int P = b * HW + (y0 + r) * 64 + x;
  unsigned int pk[4];
#pragma unroll
  for (int j = 0; j < 4; ++j)
    pk[j] = f2bf(o[2 * j] * inv) | (f2bf(o[2 * j + 1] * inv) << 16);
  *(uint4*)&ATT[(size_t)P * CDIM + h * HD + dg * 8] = make_uint4(pk[0], pk[1], pk[2], pk[3]);
}

// ---------------- wo-conv + z-residual + ffn-rmsnorm fused ----------------
// Block: 32 px, 4 waves stacked in M (each 32 Cout x 32 px). Grid 256.
__global__ __launch_bounds__(256) void wo_rms(
    const ushort* __restrict__ ATT, const ushort* __restrict__ Wb,
    const float* __restrict__ bo, const float* __restrict__ z,
    const float* __restrict__ wfn,
    float* __restrict__ ZNEW, ushort* __restrict__ FN) {
  __shared__ float sums[32][17];
  __shared__ float sinv[32];
  const int t = threadIdx.x, w = t >> 6, l = t & 63, lr = l & 15, lk = l >> 4;
  const int pblk = blockIdx.x * 32;
  const int m0 = w * 32;
  const ushort* A0 = Wb + (size_t)(m0 + lr) * 128 + lk * 8;
  const ushort* A1 = A0 + 16 * 128;
  const ushort* B0 = ATT + (size_t)(pblk + lr) * 128 + lk * 8;
  const ushort* B1 = B0 + 16 * 128;
  f32x4 acc[2][2] = {};
#pragma unroll
  for (int k0 = 0; k0 < 128; k0 += 32) {
    bf16x8 a0 = *(const bf16x8*)(A0 + k0);
    bf16x8 a1 = *(const bf16x8*)(A1 + k0);
    bf16x8 b0 = *(const bf16x8*)(B0 + k0);
    bf16x8 b1 = *(const bf16x8*)(B1 + k0);
    acc[0][0] = __builtin_amdgcn_mfma_f32_16x16x32_bf16(a0, b0, acc[0][0], 0, 0, 0);
    acc[0][1] = __builtin_amdgcn_mfma_f32_16x16x32_bf16(a0, b1, acc[0][1], 0, 0, 0);
    acc[1][0] = __builtin_amdgcn_mfma_f32_16x16x32_bf16(a1, b0, acc[1][0], 0, 0, 0);
    acc[1][1] = __builtin_amdgcn_mfma_f32_16x16x32_bf16(a1, b1, acc[1][1], 0, 0, 0);
  }
  f32x4 bv0 = *(const f32x4*)&bo[m0 + lk * 4];
  f32x4 bv1 = *(const f32x4*)&bo[m0 + 16 + lk * 4];
#pragma unroll
  for (int nf = 0; nf < 2; ++nf) {
    int P = pblk + nf * 16 + lr;
    int b = P >> 12, p = P & 4095;
    float ss = 0.f;
#pragma unroll
    for (int mf = 0; mf < 2; ++mf) {
      int row0 = m0 + mf * 16 + lk * 4;
      f32x4 bv = mf ? bv1 : bv0;
#pragma unroll
      for (int j = 0; j < 4; ++j) {
        size_t gi = ((size_t)(b * CDIM + row0 + j)) * HW + p;
        float u = acc[mf][nf][j] + bv[j] + z[gi];
        ZNEW[gi] = u;
        acc[mf][nf][j] = u;            // keep for FN write
        ss += u * u;
      }
    }
    sums[nf * 16 + lr][w * 4 + lk] = ss;
  }
  __syncthreads();
  if (t < 32) {
    float tot = 0.f;
#pragma unroll
    for (int i = 0; i < 16; ++i) tot += sums[t][i];
    sinv[t] = rsqrtf(tot * (1.0f / CDIM) + 1e-8f);
  }
  __syncthreads();
#pragma unroll
  for (int nf = 0; nf < 2; ++nf) {
    int pxl = nf * 16 + lr;
    int P = pblk + pxl;
    float inv = sinv[pxl];
#pragma unroll
    for (int mf = 0; mf < 2; ++mf) {
      int row0 = m0 + mf * 16 + lk * 4;
      f32x4 wf = *(const f32x4*)&wfn[row0];
      uint2 pk;
      float v0 = acc[mf][nf][0] * inv * wf[0];
      float v1 = acc[mf][nf][1] * inv * wf[1];
      float v2 = acc[mf][nf][2] * inv * wf[2];
      float v3 = acc[mf][nf][3] * inv * wf[3];
      pk.x = f2bf(v0) | (f2bf(v1) << 16);
      pk.y = f2bf(v2) | (f2bf(v3) << 16);
      *(uint2*)&FN[(size_t)P * CDIM + row0] = pk;
    }
  }
}

// ---------------- fused FFN: (FN x w1 + b1 -> gelu) in LDS, then x w2 + b2 + ZNEW -> out ----
// Block: 32 px. Phase1: 4 waves x (64 hid x 32 px). Phase2: 4 waves x (32 out x 32 px). Grid 256.
__global__ __launch_bounds__(256) void ffn(
    const ushort* __restrict__ FN, const ushort* __restrict__ W1b,
    const ushort* __restrict__ W2b,
    const float* __restrict__ b1, const float* __restrict__ b2,
    const float* __restrict__ ZNEW, float* __restrict__ out) {
  __shared__ ushort hid_s[32 * 256];   // 16 KiB, XOR-swizzled (idx ^ ((px&7)<<3))
  const int t = threadIdx.x, w = t >> 6, l = t & 63, lr = l & 15, lk = l >> 4;
  const int pblk = blockIdx.x * 32;
  // ---- phase 1: hid rows hm0..+64 ----
  const int hm0 = w * 64;
  const ushort* A0 = W1b + (size_t)(hm0 + lr) * 128 + lk * 8;
  const ushort* B0 = FN + (size_t)(pblk + lr) * 128 + lk * 8;
  f32x4 acc1[4][2] = {};
#pragma unroll
  for (int k0 = 0; k0 < 128; k0 += 32) {
    bf16x8 a[4], b[2];
#pragma unroll
    for (int mf = 0; mf < 4; ++mf) a[mf] = *(const bf16x8*)(A0 + mf * 16 * 128 + k0);
#pragma unroll
    for (int nf = 0; nf < 2; ++nf) b[nf] = *(const bf16x8*)(B0 + nf * 16 * 128 + k0);
#pragma unroll
    for (int mf = 0; mf < 4; ++mf)
#pragma unroll
      for (int nf = 0; nf < 2; ++nf)
        acc1[mf][nf] = __builtin_amdgcn_mfma_f32_16x16x32_bf16(a[mf], b[nf], acc1[mf][nf], 0, 0, 0);
  }
#pragma unroll
  for (int mf = 0; mf < 4; ++mf) {
    int ch0 = hm0 + mf * 16 + lk * 4;
    f32x4 bv = *(const f32x4*)&b1[ch0];
#pragma unroll
    for (int nf = 0; nf < 2; ++nf) {
      int px = nf * 16 + lr;
      float v0 = gelu_f(acc1[mf][nf][0] + bv[0]);
      float v1 = gelu_f(acc1[mf][nf][1] + bv[1]);
      float v2 = gelu_f(acc1[mf][nf][2] + bv[2]);
      float v3 = gelu_f(acc1[mf][nf][3] + bv[3]);
      uint2 pk;
      pk.x = f2bf(v0) | (f2bf(v1) << 16);
      pk.y = f2bf(v2) | (f2bf(v3) << 16);
      int idx = (px * 256 + ch0) ^ ((px & 7) << 3);
      *(uint2*)&hid_s[idx] = pk;
    }
  }
  __syncthreads();
  // ---- phase 2: out rows om0..+32, K=256 from LDS ----
  const int om0 = w * 32;
  const ushort* C0 = W2b + (size_t)(om0 + lr) * 256 + lk * 8;
  f32x4 acc2[2][2] = {};
#pragma unroll
  for (int k0 = 0; k0 < 256; k0 += 32) {
    bf16x8 a0 = *(const bf16x8*)(C0 + k0);
    bf16x8 a1 = *(const bf16x8*)(C0 + 16 * 256 + k0);
    bf16x8 b[2];
#pragma unroll
    for (int nf = 0; nf < 2; ++nf) {
      int px = nf * 16 + lr;
      int idx = (px * 256 + k0 + lk * 8) ^ ((px & 7) << 3);
      b[nf] = *(const bf16x8*)&hid_s[idx];
    }
    acc2[0][0] = __builtin_amdgcn_mfma_f32_16x16x32_bf16(a0, b[0], acc2[0][0], 0, 0, 0);
    acc2[0][1] = __builtin_amdgcn_mfma_f32_16x16x32_bf16(a0, b[1], acc2[0][1], 0, 0, 0);
    acc2[1][0] = __builtin_amdgcn_mfma_f32_16x16x32_bf16(a1, b[0], acc2[1][0], 0, 0, 0);
    acc2[1][1] = __builtin_amdgcn_mfma_f32_16x16x32_bf16(a1, b[1], acc2[1][1], 0, 0, 0);
  }
#pragma unroll
  for (int mf = 0; mf < 2; ++mf) {
    int row0 = om0 + mf * 16 + lk * 4;
    f32x4 bv = *(const f32x4*)&b2[row0];
#pragma unroll
    for (int nf = 0; nf < 2; ++nf) {
      int P = pblk + nf * 16 + lr;
      int b_ = P >> 12, p = P & 4095;
#pragma unroll
      for (int j = 0; j < 4; ++j) {
        size_t gi = ((size_t)(b_ * CDIM + row0 + j)) * HW + p;
        out[gi] = acc2[mf][nf][j] + bv[j] + ZNEW[gi];
      }
    }
  }
}

// ---------------- launch ----------------
extern "C" void kernel_launch(void* const* d_in, const int* in_sizes, int n_in,
                              void* d_out, int out_size, void* d_ws, size_t ws_size,
                              hipStream_t stream) {
  const float* z   = (const float*)d_in[0];
  const float* h   = (const float*)d_in[1];
  const float* wzn = (const float*)d_in[2];
  const float* whn = (const float*)d_in[3];
  const float* wq  = (const float*)d_in[4];
  const float* bq  = (const float*)d_in[5];
  const float* wk  = (const float*)d_in[6];
  const float* bk  = (const float*)d_in[7];
  const float* wv  = (const float*)d_in[8];
  const float* bv  = (const float*)d_in[9];
  const float* wo  = (const float*)d_in[10];
  const float* bo  = (const float*)d_in[11];
  const float* wfn = (const float*)d_in[12];
  const float* w1  = (const float*)d_in[13];
  const float* b1  = (const float*)d_in[14];
  const float* w2  = (const float*)d_in[15];
  const float* b2  = (const float*)d_in[16];
  float* out = (float*)d_out;
  float* ws  = (float*)d_ws;

  const size_t SL = 1048576;                 // one fp32 [2][128][4096] tensor (floats)
  float*  Qf   = ws + 0 * SL;
  float*  Kf   = ws + 1 * SL;
  float*  Vf   = ws + 2 * SL;
  float*  ZNEW = ws + 3 * SL;
  ushort* ZN   = (ushort*)(ws + 4 * SL);     // 1M ushorts each
  ushort* HN   = ZN  + 1048576;
  ushort* ATT  = HN  + 1048576;
  ushort* FN   = ATT + 1048576;
  ushort* WB   = FN  + 1048576;              // 131072 ushorts

  prep<<<dim3(384), 256, 0, stream>>>(wq, wk, wv, wo, w1, w2, WB, z, wzn, ZN, h, whn, HN);
  qkv_mm<<<dim3(64, 2, 3), 256, 0, stream>>>(ZN, HN, WB, bq, bk, bv, Qf, Kf, Vf);
  nattn<<<dim3(32, HEADS, 2), 512, 0, stream>>>(Qf, Kf, Vf, ATT);
  wo_rms<<<dim3(256), 256, 0, stream>>>(ATT, WB + 49152, bo, z, wfn, ZNEW, FN);
  ffn<<<dim3(256), 256, 0, stream>>>(FN, WB + 65536, WB + 98304, b1, b2, ZNEW, out);
}

// Round 6
// 48.581 us; speedup vs baseline: 6.9856x; 1.0473x over previous
//
#include <hip/hip_runtime.h>
#include <math.h>

#define CDIM 128
#define HW   4096
#define HEADS 4
#define HD   32

typedef __attribute__((ext_vector_type(8))) short bf16x8;
typedef __attribute__((ext_vector_type(4))) float f32x4;

static __device__ __forceinline__ unsigned int f2bf(float f) {
  union { float f; unsigned int u; } v; v.f = f;
  unsigned int r = v.u + 0x7FFF + ((v.u >> 16) & 1);   // RNE
  return r >> 16;
}
static __device__ __forceinline__ float bflo(unsigned int u) {
  return __uint_as_float(u << 16);
}
static __device__ __forceinline__ float bfhi(unsigned int u) {
  return __uint_as_float(u & 0xFFFF0000u);
}
static __device__ __forceinline__ float gelu_f(float v) {
  return 0.5f * v * (1.0f + erff(v * 0.70710678118654752f));
}

// ---------------- prep: wcvt (blocks 0..127) + rmsnorm z (128..255) + rmsnorm h (256..383) ----
// WB ushort offsets: wq 0, wk 16384, wv 32768, wo 49152, w1 65536, w2 98304.
__global__ __launch_bounds__(256) void prep(
    const float* __restrict__ wq, const float* __restrict__ wk,
    const float* __restrict__ wv, const float* __restrict__ wo,
    const float* __restrict__ w1, const float* __restrict__ w2,
    ushort* __restrict__ WB,
    const float* __restrict__ z, const float* __restrict__ wzn, ushort* __restrict__ ZN,
    const float* __restrict__ h, const float* __restrict__ whn, ushort* __restrict__ HN) {
  __shared__ float sh[4][64];
  const int bx = blockIdx.x, t = threadIdx.x;
  if (bx < 128) {
    int e = (bx * 256 + t) * 4;
    const float* src; int off;
    if      (e < 16384) { src = wq; off = 0; }
    else if (e < 32768) { src = wk; off = 16384; }
    else if (e < 49152) { src = wv; off = 32768; }
    else if (e < 65536) { src = wo; off = 49152; }
    else if (e < 98304) { src = w1; off = 65536; }
    else                { src = w2; off = 98304; }
    float4 v = *(const float4*)&src[e - off];
    uint2 r;
    r.x = f2bf(v.x) | (f2bf(v.y) << 16);
    r.y = f2bf(v.z) | (f2bf(v.w) << 16);
    *(uint2*)&WB[e] = r;
    return;
  }
  int gblk = bx - 128;
  const float* x; const float* w; ushort* o;
  if (gblk < 128) { x = z; w = wzn; o = ZN; }
  else            { x = h; w = whn; o = HN; gblk -= 128; }
  int pl = t & 63;
  int g  = t >> 6;
  int gp = gblk * 64 + pl;                // global pixel (b*4096 + p)
  size_t base = (size_t)(gp >> 12) * CDIM * HW + (gp & 4095);
  const float* xb = x + base;
  float vals[32];
  float ss = 0.f;
#pragma unroll
  for (int j = 0; j < 32; ++j) {
    float v = xb[(size_t)(g * 32 + j) * HW];
    vals[j] = v;
    ss += v * v;
  }
  sh[g][pl] = ss;
  __syncthreads();
  float tot = sh[0][pl] + sh[1][pl] + sh[2][pl] + sh[3][pl];
  float inv = rsqrtf(tot * (1.0f / CDIM) + 1e-8f);
  unsigned int pk[16];
#pragma unroll
  for (int j = 0; j < 16; ++j) {
    float a = vals[2 * j]     * inv * w[g * 32 + 2 * j];
    float b = vals[2 * j + 1] * inv * w[g * 32 + 2 * j + 1];
    pk[j] = f2bf(a) | (f2bf(b) << 16);
  }
  unsigned int* dst = (unsigned int*)&o[(size_t)gp * CDIM + g * 32];
#pragma unroll
  for (int q = 0; q < 4; ++q)
    *(uint4*)(dst + q * 4) = make_uint4(pk[q*4], pk[q*4+1], pk[q*4+2], pk[q*4+3]);
}

// ---------------- MFMA qkv: X[P][128] bf16 x W[Cout][128] bf16 -> bf16 [P][c] ----------------
// Block 256 = 4 waves (2M x 2N). Wave tile 32 Cout x 64 px.
__device__ __forceinline__ void mm_body_qkv(
    const ushort* __restrict__ X, const ushort* __restrict__ Wb,
    const float* __restrict__ bias, ushort* __restrict__ outB,
    int pblk, int mblk) {
  const int t  = threadIdx.x;
  const int w  = t >> 6;
  const int wm = w & 1, wn = w >> 1;
  const int l  = t & 63;
  const int lr = l & 15, lk = l >> 4;
  const int m0 = mblk + wm * 32;
  const int p0 = pblk + wn * 64;

  const ushort* A0 = Wb + (size_t)(m0 + lr) * 128 + lk * 8;
  const ushort* A1 = A0 + 16 * 128;
  const ushort* B0 = X + (size_t)(p0 + lr) * 128 + lk * 8;

  f32x4 acc[2][4] = {};
#pragma unroll
  for (int k0 = 0; k0 < 128; k0 += 32) {
    bf16x8 a0 = *(const bf16x8*)(A0 + k0);
    bf16x8 a1 = *(const bf16x8*)(A1 + k0);
    bf16x8 b[4];
#pragma unroll
    for (int nf = 0; nf < 4; ++nf) b[nf] = *(const bf16x8*)(B0 + nf * 16 * 128 + k0);
#pragma unroll
    for (int nf = 0; nf < 4; ++nf) {
      acc[0][nf] = __builtin_amdgcn_mfma_f32_16x16x32_bf16(a0, b[nf], acc[0][nf], 0, 0, 0);
      acc[1][nf] = __builtin_amdgcn_mfma_f32_16x16x32_bf16(a1, b[nf], acc[1][nf], 0, 0, 0);
    }
  }
#pragma unroll
  for (int mf = 0; mf < 2; ++mf) {
    int obase = m0 + mf * 16 + lk * 4;
    f32x4 bv = *(const f32x4*)&bias[obase];
#pragma unroll
    for (int nf = 0; nf < 4; ++nf) {
      int P = p0 + nf * 16 + lr;
      uint2 pk;
      pk.x = f2bf(acc[mf][nf][0] + bv[0]) | (f2bf(acc[mf][nf][1] + bv[1]) << 16);
      pk.y = f2bf(acc[mf][nf][2] + bv[2]) | (f2bf(acc[mf][nf][3] + bv[3]) << 16);
      *(uint2*)&outB[(size_t)P * CDIM + obase] = pk;
    }
  }
}

// fused q/k/v: grid (64, 2, 3); sel 0=q(ZN) 1=k(HN) 2=v(HN); bf16 [P][c] outputs
__global__ __launch_bounds__(256) void qkv_mm(
    const ushort* __restrict__ ZN, const ushort* __restrict__ HN,
    const ushort* __restrict__ WB,
    const float* __restrict__ bq, const float* __restrict__ bk, const float* __restrict__ bv,
    ushort* __restrict__ Qb, ushort* __restrict__ Kb, ushort* __restrict__ Vb) {
  int sel = blockIdx.z;
  const ushort* X = (sel == 0) ? ZN : HN;
  const ushort* W = WB + sel * 16384;
  const float* bias = (sel == 0) ? bq : (sel == 1 ? bk : bv);
  ushort* out = (sel == 0) ? Qb : (sel == 1 ? Kb : Vb);
  mm_body_qkv(X, W, bias, out, blockIdx.x * 128, blockIdx.y * 64);
}

// ---------------- neighborhood attention v4: bf16-pair-packed LDS K/V ----------------
// Block = (2 rows, head, batch): 512 thr = 128 px * 4 d-groups. LDS 64 KiB.
// smem uints: K-packed [dp=16][yy=8][x=64] | V-packed same at +8192.
// sS float [49][128] aliases the K region (barrier-separated).
__global__ __launch_bounds__(512) void nattn(
    const ushort* __restrict__ Q, const ushort* __restrict__ K,
    const ushort* __restrict__ V, ushort* __restrict__ ATT) {
  __shared__ unsigned int smem[16384];   // 64 KiB
  float* sS = (float*)smem;
  const int t  = threadIdx.x;
  const int px = t & 127;
  const int x  = px & 63;
  const int r  = px >> 6;
  const int dg = t >> 7;          // 0..3
  const int y0 = blockIdx.x * 2;
  const int h  = blockIdx.y;
  const int b  = blockIdx.z;
  const int ybase = y0 - 3;

  // ---- stage K,V halo: thread t -> tile pixel (yy, xs); 16 packed uints each ----
  {
    int yy = t >> 6, xs = t & 63;
    int gy = min(max(ybase + yy, 0), 63);
    int P  = b * HW + gy * 64 + xs;
    const uint4* ks = (const uint4*)&K[(size_t)P * CDIM + h * HD];
    const uint4* vs = (const uint4*)&V[(size_t)P * CDIM + h * HD];
    int base0 = yy * 64 + xs;
#pragma unroll
    for (int i = 0; i < 4; ++i) {
      uint4 kv = ks[i];
      uint4 vv = vs[i];
      int o0 = i * 4 * 512 + base0;
      smem[o0]        = kv.x;  smem[o0 + 512]  = kv.y;
      smem[o0 + 1024] = kv.z;  smem[o0 + 1536] = kv.w;
      smem[8192 + o0]        = vv.x;  smem[8192 + o0 + 512]  = vv.y;
      smem[8192 + o0 + 1024] = vv.z;  smem[8192 + o0 + 1536] = vv.w;
    }
  }
  // ---- q into regs (4 x uint4, unpack to 32 f32) ----
  const int Pq = b * HW + (y0 + r) * 64 + x;
  const uint4* qs = (const uint4*)&Q[(size_t)Pq * CDIM + h * HD];
  float q[32];
#pragma unroll
  for (int i = 0; i < 4; ++i) {
    uint4 u4 = qs[i];
    q[i*8+0] = bflo(u4.x); q[i*8+1] = bfhi(u4.x);
    q[i*8+2] = bflo(u4.y); q[i*8+3] = bfhi(u4.y);
    q[i*8+4] = bflo(u4.z); q[i*8+5] = bfhi(u4.z);
    q[i*8+6] = bflo(u4.w); q[i*8+7] = bfhi(u4.w);
  }
  __syncthreads();

  // ---- scores: 13/12/12/12 neighbors per d-group ----
  const float scale = 0.17677669529663687f;
  const int nb0    = (dg == 0) ? 0 : dg * 12 + 1;
  const int ncount = (dg == 0) ? 13 : 12;
  float sreg[13];
#pragma unroll
  for (int j = 0; j < 13; ++j) {
    if (j < ncount) {
      int nb = nb0 + j;
      int dy = nb / 7 - 3;
      int dx = nb % 7 - 3;
      int ry = r + dy + 3;
      int nx = x + dx;
      int xx = min(max(nx, 0), 63);
      int ny = y0 + r + dy;
      bool valid = (ny >= 0) && (ny <= 63) && (nx >= 0) && (nx <= 63);
      const unsigned int* kb = &smem[ry * 64 + xx];
      float acc = 0.f;
#pragma unroll
      for (int dp = 0; dp < 16; ++dp) {
        unsigned int u = kb[dp * 512];
        acc += q[2*dp]   * bflo(u);
        acc += q[2*dp+1] * bfhi(u);
      }
      sreg[j] = valid ? acc * scale : -1e30f;
    }
  }
  __syncthreads();                   // all K reads done before sS overlay
#pragma unroll
  for (int j = 0; j < 13; ++j)
    if (j < ncount) sS[(nb0 + j) * 128 + px] = sreg[j];
  __syncthreads();

  // ---- streamed softmax (fixed m=8; |s|<~3, overflow-safe to s<96) + PV ----
  float o[8] = {0.f, 0.f, 0.f, 0.f, 0.f, 0.f, 0.f, 0.f};
  float sum = 0.f;
#pragma unroll
  for (int nb = 0; nb < 49; ++nb) {
    float p = __expf(sS[nb * 128 + px] - 8.0f);   // invalid -1e30 -> exp = 0
    sum += p;
    int ry = r + nb / 7;                          // nb static: compile-time div/mod
    int xx = min(max(x + nb % 7 - 3, 0), 63);
    const unsigned int* vb = &smem[8192 + dg * 2048 + ry * 64 + xx];
#pragma unroll
    for (int m = 0; m < 4; ++m) {
      unsigned int u = vb[m * 512];
      o[2*m]   += p * bflo(u);
      o[2*m+1] += p * bfhi(u);
    }
  }
  float inv = 1.0f / sum;
  unsigned int pk[4];
#pragma unroll
  for (int j = 0; j < 4; ++j)
    pk[j] = f2bf(o[2*j] * inv) | (f2bf(o[2*j+1] * inv) << 16);
  *(uint4*)&ATT[(size_t)Pq * CDIM + h * HD + dg * 8] = make_uint4(pk[0], pk[1], pk[2], pk[3]);
}

// ---------------- wo-conv + z-residual + ffn-rmsnorm fused ----------------
// Block: 32 px, 4 waves stacked in M (each 32 Cout x 32 px). Grid 256.
__global__ __launch_bounds__(256) void wo_rms(
    const ushort* __restrict__ ATT, const ushort* __restrict__ Wb,
    const float* __restrict__ bo, const float* __restrict__ z,
    const float* __restrict__ wfn,
    float* __restrict__ ZNEW, ushort* __restrict__ FN) {
  __shared__ float sums[32][17];
  __shared__ float sinv[32];
  const int t = threadIdx.x, w = t >> 6, l = t & 63, lr = l & 15, lk = l >> 4;
  const int pblk = blockIdx.x * 32;
  const int m0 = w * 32;
  const ushort* A0 = Wb + (size_t)(m0 + lr) * 128 + lk * 8;
  const ushort* A1 = A0 + 16 * 128;
  const ushort* B0 = ATT + (size_t)(pblk + lr) * 128 + lk * 8;
  const ushort* B1 = B0 + 16 * 128;
  f32x4 acc[2][2] = {};
#pragma unroll
  for (int k0 = 0; k0 < 128; k0 += 32) {
    bf16x8 a0 = *(const bf16x8*)(A0 + k0);
    bf16x8 a1 = *(const bf16x8*)(A1 + k0);
    bf16x8 b0 = *(const bf16x8*)(B0 + k0);
    bf16x8 b1 = *(const bf16x8*)(B1 + k0);
    acc[0][0] = __builtin_amdgcn_mfma_f32_16x16x32_bf16(a0, b0, acc[0][0], 0, 0, 0);
    acc[0][1] = __builtin_amdgcn_mfma_f32_16x16x32_bf16(a0, b1, acc[0][1], 0, 0, 0);
    acc[1][0] = __builtin_amdgcn_mfma_f32_16x16x32_bf16(a1, b0, acc[1][0], 0, 0, 0);
    acc[1][1] = __builtin_amdgcn_mfma_f32_16x16x32_bf16(a1, b1, acc[1][1], 0, 0, 0);
  }
  f32x4 bv0 = *(const f32x4*)&bo[m0 + lk * 4];
  f32x4 bv1 = *(const f32x4*)&bo[m0 + 16 + lk * 4];
#pragma unroll
  for (int nf = 0; nf < 2; ++nf) {
    int P = pblk + nf * 16 + lr;
    int b = P >> 12, p = P & 4095;
    float ss = 0.f;
#pragma unroll
    for (int mf = 0; mf < 2; ++mf) {
      int row0 = m0 + mf * 16 + lk * 4;
      f32x4 bv = mf ? bv1 : bv0;
#pragma unroll
      for (int j = 0; j < 4; ++j) {
        size_t gi = ((size_t)(b * CDIM + row0 + j)) * HW + p;
        float u = acc[mf][nf][j] + bv[j] + z[gi];
        ZNEW[gi] = u;
        acc[mf][nf][j] = u;            // keep for FN write
        ss += u * u;
      }
    }
    sums[nf * 16 + lr][w * 4 + lk] = ss;
  }
  __syncthreads();
  if (t < 32) {
    float tot = 0.f;
#pragma unroll
    for (int i = 0; i < 16; ++i) tot += sums[t][i];
    sinv[t] = rsqrtf(tot * (1.0f / CDIM) + 1e-8f);
  }
  __syncthreads();
#pragma unroll
  for (int nf = 0; nf < 2; ++nf) {
    int pxl = nf * 16 + lr;
    int P = pblk + pxl;
    float inv = sinv[pxl];
#pragma unroll
    for (int mf = 0; mf < 2; ++mf) {
      int row0 = m0 + mf * 16 + lk * 4;
      f32x4 wf = *(const f32x4*)&wfn[row0];
      uint2 pk;
      float v0 = acc[mf][nf][0] * inv * wf[0];
      float v1 = acc[mf][nf][1] * inv * wf[1];
      float v2 = acc[mf][nf][2] * inv * wf[2];
      float v3 = acc[mf][nf][3] * inv * wf[3];
      pk.x = f2bf(v0) | (f2bf(v1) << 16);
      pk.y = f2bf(v2) | (f2bf(v3) << 16);
      *(uint2*)&FN[(size_t)P * CDIM + row0] = pk;
    }
  }
}

// ---------------- fused FFN: (FN x w1 + b1 -> gelu) in LDS, then x w2 + b2 + ZNEW -> out ----
__global__ __launch_bounds__(256) void ffn(
    const ushort* __restrict__ FN, const ushort* __restrict__ W1b,
    const ushort* __restrict__ W2b,
    const float* __restrict__ b1, const float* __restrict__ b2,
    const float* __restrict__ ZNEW, float* __restrict__ out) {
  __shared__ ushort hid_s[32 * 256];   // 16 KiB, XOR-swizzled (idx ^ ((px&7)<<3))
  const int t = threadIdx.x, w = t >> 6, l = t & 63, lr = l & 15, lk = l >> 4;
  const int pblk = blockIdx.x * 32;
  // ---- phase 1: hid rows hm0..+64 ----
  const int hm0 = w * 64;
  const ushort* A0 = W1b + (size_t)(hm0 + lr) * 128 + lk * 8;
  const ushort* B0 = FN + (size_t)(pblk + lr) * 128 + lk * 8;
  f32x4 acc1[4][2] = {};
#pragma unroll
  for (int k0 = 0; k0 < 128; k0 += 32) {
    bf16x8 a[4], b[2];
#pragma unroll
    for (int mf = 0; mf < 4; ++mf) a[mf] = *(const bf16x8*)(A0 + mf * 16 * 128 + k0);
#pragma unroll
    for (int nf = 0; nf < 2; ++nf) b[nf] = *(const bf16x8*)(B0 + nf * 16 * 128 + k0);
#pragma unroll
    for (int mf = 0; mf < 4; ++mf)
#pragma unroll
      for (int nf = 0; nf < 2; ++nf)
        acc1[mf][nf] = __builtin_amdgcn_mfma_f32_16x16x32_bf16(a[mf], b[nf], acc1[mf][nf], 0, 0, 0);
  }
#pragma unroll
  for (int mf = 0; mf < 4; ++mf) {
    int ch0 = hm0 + mf * 16 + lk * 4;
    f32x4 bv = *(const f32x4*)&b1[ch0];
#pragma unroll
    for (int nf = 0; nf < 2; ++nf) {
      int px = nf * 16 + lr;
      float v0 = gelu_f(acc1[mf][nf][0] + bv[0]);
      float v1 = gelu_f(acc1[mf][nf][1] + bv[1]);
      float v2 = gelu_f(acc1[mf][nf][2] + bv[2]);
      float v3 = gelu_f(acc1[mf][nf][3] + bv[3]);
      uint2 pk;
      pk.x = f2bf(v0) | (f2bf(v1) << 16);
      pk.y = f2bf(v2) | (f2bf(v3) << 16);
      int idx = (px * 256 + ch0) ^ ((px & 7) << 3);
      *(uint2*)&hid_s[idx] = pk;
    }
  }
  __syncthreads();
  // ---- phase 2: out rows om0..+32, K=256 from LDS ----
  const int om0 = w * 32;
  const ushort* C0 = W2b + (size_t)(om0 + lr) * 256 + lk * 8;
  f32x4 acc2[2][2] = {};
#pragma unroll
  for (int k0 = 0; k0 < 256; k0 += 32) {
    bf16x8 a0 = *(const bf16x8*)(C0 + k0);
    bf16x8 a1 = *(const bf16x8*)(C0 + 16 * 256 + k0);
    bf16x8 b[2];
#pragma unroll
    for (int nf = 0; nf < 2; ++nf) {
      int px = nf * 16 + lr;
      int idx = (px * 256 + k0 + lk * 8) ^ ((px & 7) << 3);
      b[nf] = *(const bf16x8*)&hid_s[idx];
    }
    acc2[0][0] = __builtin_amdgcn_mfma_f32_16x16x32_bf16(a0, b[0], acc2[0][0], 0, 0, 0);
    acc2[0][1] = __builtin_amdgcn_mfma_f32_16x16x32_bf16(a0, b[1], acc2[0][1], 0, 0, 0);
    acc2[1][0] = __builtin_amdgcn_mfma_f32_16x16x32_bf16(a1, b[0], acc2[1][0], 0, 0, 0);
    acc2[1][1] = __builtin_amdgcn_mfma_f32_16x16x32_bf16(a1, b[1], acc2[1][1], 0, 0, 0);
  }
#pragma unroll
  for (int mf = 0; mf < 2; ++mf) {
    int row0 = om0 + mf * 16 + lk * 4;
    f32x4 bv = *(const f32x4*)&b2[row0];
#pragma unroll
    for (int nf = 0; nf < 2; ++nf) {
      int P = pblk + nf * 16 + lr;
      int b_ = P >> 12, p = P & 4095;
#pragma unroll
      for (int j = 0; j < 4; ++j) {
        size_t gi = ((size_t)(b_ * CDIM + row0 + j)) * HW + p;
        out[gi] = acc2[mf][nf][j] + bv[j] + ZNEW[gi];
      }
    }
  }
}

// ---------------- launch ----------------
extern "C" void kernel_launch(void* const* d_in, const int* in_sizes, int n_in,
                              void* d_out, int out_size, void* d_ws, size_t ws_size,
                              hipStream_t stream) {
  const float* z   = (const float*)d_in[0];
  const float* h   = (const float*)d_in[1];
  const float* wzn = (const float*)d_in[2];
  const float* whn = (const float*)d_in[3];
  const float* wq  = (const float*)d_in[4];
  const float* bq  = (const float*)d_in[5];
  const float* wk  = (const float*)d_in[6];
  const float* bk  = (const float*)d_in[7];
  const float* wv  = (const float*)d_in[8];
  const float* bv  = (const float*)d_in[9];
  const float* wo  = (const float*)d_in[10];
  const float* bo  = (const float*)d_in[11];
  const float* wfn = (const float*)d_in[12];
  const float* w1  = (const float*)d_in[13];
  const float* b1  = (const float*)d_in[14];
  const float* w2  = (const float*)d_in[15];
  const float* b2  = (const float*)d_in[16];
  float* out = (float*)d_out;

  const size_t U = 1048576;                  // one [8192][128] bf16 tensor (ushorts)
  ushort* Qb  = (ushort*)d_ws;
  ushort* Kb  = Qb + U;
  ushort* Vb  = Kb + U;
  ushort* ZN  = Vb + U;
  ushort* HN  = ZN + U;
  ushort* ATT = HN + U;
  ushort* FN  = ATT + U;
  ushort* WB  = FN + U;                      // 131072 ushorts
  float* ZNEW = (float*)(WB + 131072);       // 1M floats

  prep<<<dim3(384), 256, 0, stream>>>(wq, wk, wv, wo, w1, w2, WB, z, wzn, ZN, h, whn, HN);
  qkv_mm<<<dim3(64, 2, 3), 256, 0, stream>>>(ZN, HN, WB, bq, bk, bv, Qb, Kb, Vb);
  nattn<<<dim3(32, HEADS, 2), 512, 0, stream>>>(Qb, Kb, Vb, ATT);
  wo_rms<<<dim3(256), 256, 0, stream>>>(ATT, WB + 49152, bo, z, wfn, ZNEW, FN);
  ffn<<<dim3(256), 256, 0, stream>>>(FN, WB + 65536, WB + 98304, b1, b2, ZNEW, out);
}

// Round 7
// 40.592 us; speedup vs baseline: 8.3605x; 1.1968x over previous
//
#include <hip/hip_runtime.h>
#include <math.h>

#define CDIM 128
#define HW   4096
#define HEADS 4
#define HD   32

typedef __attribute__((ext_vector_type(8))) short bf16x8;
typedef __attribute__((ext_vector_type(4))) float f32x4;

static __device__ __forceinline__ unsigned int f2bf(float f) {
  union { float f; unsigned int u; } v; v.f = f;
  unsigned int r = v.u + 0x7FFF + ((v.u >> 16) & 1);   // RNE
  return r >> 16;
}
static __device__ __forceinline__ float bflo(unsigned int u) {
  return __uint_as_float(u << 16);
}
static __device__ __forceinline__ float bfhi(unsigned int u) {
  return __uint_as_float(u & 0xFFFF0000u);
}
static __device__ __forceinline__ float gelu_f(float v) {
  return 0.5f * v * (1.0f + erff(v * 0.70710678118654752f));
}

// ================= head: rmsnorm + qkv GEMM fused; y==3 slice converts tail weights =====
// grid (128, 4), block 256. y=0: q from z; y=1: k from h; y=2: v from h.
// Block: 64 px, full 128 Cout (4 waves stacked in M). W converted fp32->bf16 into LDS.
__global__ __launch_bounds__(256) void head(
    const float* __restrict__ z, const float* __restrict__ h,
    const float* __restrict__ wzn, const float* __restrict__ whn,
    const float* __restrict__ wq, const float* __restrict__ bq,
    const float* __restrict__ wk, const float* __restrict__ bk,
    const float* __restrict__ wv, const float* __restrict__ bv,
    const float* __restrict__ wo, const float* __restrict__ w1,
    const float* __restrict__ w2, ushort* __restrict__ WB,
    ushort* __restrict__ Qb, ushort* __restrict__ Kb, ushort* __restrict__ Vb) {
  const int sel = blockIdx.y, t = threadIdx.x;
  if (sel == 3) {
    // convert wo (16384) | w1 (32768) | w2 (32768) into WB+49152 (contiguous map)
    int e = (blockIdx.x * 256 + t) * 4;
    if (e < 81920) {
      const float* src; int off;
      if      (e < 16384) { src = wo; off = 0; }
      else if (e < 49152) { src = w1; off = 16384; }
      else                { src = w2; off = 49152; }
      float4 v = *(const float4*)&src[e - off];
      uint2 r;
      r.x = f2bf(v.x) | (f2bf(v.y) << 16);
      r.y = f2bf(v.z) | (f2bf(v.w) << 16);
      *(uint2*)&WB[49152 + e] = r;
    }
    return;
  }
  __shared__ __align__(16) ushort sW[128 * 128];   // [out][k] bf16, XOR-swizzled
  __shared__ __align__(16) ushort sX[64 * 128];    // [px][ch] bf16, XOR-swizzled
  __shared__ float sh[4][64];

  const float* X    = (sel == 0) ? z : h;
  const float* wn   = (sel == 0) ? wzn : whn;
  const float* Wf   = (sel == 0) ? wq : (sel == 1 ? wk : wv);
  const float* bias = (sel == 0) ? bq : (sel == 1 ? bk : bv);
  ushort* outB      = (sel == 0) ? Qb : (sel == 1 ? Kb : Vb);

  // ---- stage W: fp32 global -> bf16 LDS (swizzled rows) ----
#pragma unroll
  for (int i = 0; i < 8; ++i) {
    int u  = t + i * 256;                  // 2048 chunks of 8 elems
    int o  = u >> 4;
    int k8 = (u & 15) * 8;
    float4 v0 = *(const float4*)&Wf[o * 128 + k8];
    float4 v1 = *(const float4*)&Wf[o * 128 + k8 + 4];
    uint4 pk;
    pk.x = f2bf(v0.x) | (f2bf(v0.y) << 16);
    pk.y = f2bf(v0.z) | (f2bf(v0.w) << 16);
    pk.z = f2bf(v1.x) | (f2bf(v1.y) << 16);
    pk.w = f2bf(v1.z) | (f2bf(v1.w) << 16);
    int idx = (o * 128 + k8) ^ ((o & 7) << 3);
    *(uint4*)&sW[idx] = pk;
  }

  // ---- rmsnorm 64 pixels (prep-proven structure) -> sX bf16 [px][ch] swizzled ----
  const int pl = t & 63, g = t >> 6;
  const int gp = blockIdx.x * 64 + pl;     // global pixel (b*4096 + p)
  const size_t xbase = (size_t)(gp >> 12) * CDIM * HW + (gp & 4095);
  float vals[32];
  float ss = 0.f;
#pragma unroll
  for (int j = 0; j < 32; ++j) {
    float v = X[xbase + (size_t)(g * 32 + j) * HW];
    vals[j] = v;
    ss += v * v;
  }
  sh[g][pl] = ss;
  __syncthreads();
  float tot = sh[0][pl] + sh[1][pl] + sh[2][pl] + sh[3][pl];
  float inv = rsqrtf(tot * (1.0f / CDIM) + 1e-8f);
#pragma unroll
  for (int jj = 0; jj < 4; ++jj) {
    unsigned int u[4];
#pragma unroll
    for (int p2 = 0; p2 < 4; ++p2) {
      int j = jj * 8 + p2 * 2;
      float a = vals[j]     * inv * wn[g * 32 + j];
      float b = vals[j + 1] * inv * wn[g * 32 + j + 1];
      u[p2] = f2bf(a) | (f2bf(b) << 16);
    }
    int idx = (pl * 128 + g * 32 + jj * 8) ^ ((pl & 7) << 3);
    *(uint4*)&sX[idx] = make_uint4(u[0], u[1], u[2], u[3]);
  }
  __syncthreads();

  // ---- MFMA: wave w -> 32 Cout x 64 px ----
  const int w = t >> 6, l = t & 63, lr = l & 15, lk = l >> 4;
  const int m0 = w * 32;
  const int swz = (lr & 7) << 3;           // (row&7)<<3 with row%8 == lr%8 everywhere
  f32x4 acc[2][4] = {};
#pragma unroll
  for (int k0 = 0; k0 < 128; k0 += 32) {
    bf16x8 a0 = *(const bf16x8*)&sW[((m0 + lr) * 128 + k0 + lk * 8) ^ swz];
    bf16x8 a1 = *(const bf16x8*)&sW[((m0 + 16 + lr) * 128 + k0 + lk * 8) ^ swz];
    bf16x8 b[4];
#pragma unroll
    for (int nf = 0; nf < 4; ++nf)
      b[nf] = *(const bf16x8*)&sX[((nf * 16 + lr) * 128 + k0 + lk * 8) ^ swz];
#pragma unroll
    for (int nf = 0; nf < 4; ++nf) {
      acc[0][nf] = __builtin_amdgcn_mfma_f32_16x16x32_bf16(a0, b[nf], acc[0][nf], 0, 0, 0);
      acc[1][nf] = __builtin_amdgcn_mfma_f32_16x16x32_bf16(a1, b[nf], acc[1][nf], 0, 0, 0);
    }
  }
#pragma unroll
  for (int mf = 0; mf < 2; ++mf) {
    int obase = m0 + mf * 16 + lk * 4;
    f32x4 bv = *(const f32x4*)&bias[obase];
#pragma unroll
    for (int nf = 0; nf < 4; ++nf) {
      int P = blockIdx.x * 64 + nf * 16 + lr;
      uint2 pk;
      pk.x = f2bf(acc[mf][nf][0] + bv[0]) | (f2bf(acc[mf][nf][1] + bv[1]) << 16);
      pk.y = f2bf(acc[mf][nf][2] + bv[2]) | (f2bf(acc[mf][nf][3] + bv[3]) << 16);
      *(uint2*)&outB[(size_t)P * CDIM + obase] = pk;
    }
  }
}

// ================= neighborhood attention v5: per-pixel-packed LDS, b128 reads =========
// Block = (2 rows, head, batch): 512 thr = 128 px * 4 d-groups. LDS 80 KiB.
// K at [yy][x][20 uints] (16 data + 4 pad), V same at +10240. sS[49][128] f32 aliases K.
__global__ __launch_bounds__(512) void nattn(
    const ushort* __restrict__ Q, const ushort* __restrict__ K,
    const ushort* __restrict__ V, ushort* __restrict__ ATT) {
  __shared__ __align__(16) unsigned int smem[20480];   // 80 KiB
  float* sS = (float*)smem;
  const int t  = threadIdx.x;
  const int px = t & 127;
  const int x  = px & 63;
  const int r  = px >> 6;
  const int dg = t >> 7;          // 0..3
  const int y0 = blockIdx.x * 2;
  const int h  = blockIdx.y;
  const int b  = blockIdx.z;
  const int ybase = y0 - 3;

  // ---- stage: one halo pixel per thread; 16+16 packed uints, b128 writes ----
  {
    int yy = t >> 6, xs = t & 63;
    int gy = min(max(ybase + yy, 0), 63);
    size_t gb = ((size_t)(b * HW + gy * 64 + xs)) * 64 + h * 16;   // uint units
    const unsigned int* Ku = (const unsigned int*)K;
    const unsigned int* Vu = (const unsigned int*)V;
    int lb = (yy * 64 + xs) * 20;
#pragma unroll
    for (int i = 0; i < 4; ++i) {
      uint4 kv = *(const uint4*)&Ku[gb + i * 4];
      uint4 vv = *(const uint4*)&Vu[gb + i * 4];
      *(uint4*)&smem[lb + i * 4]         = kv;
      *(uint4*)&smem[10240 + lb + i * 4] = vv;
    }
  }
  // ---- q into regs ----
  const int Pq = b * HW + (y0 + r) * 64 + x;
  const unsigned int* Qu = (const unsigned int*)Q;
  float q[32];
#pragma unroll
  for (int i = 0; i < 4; ++i) {
    uint4 u4 = *(const uint4*)&Qu[(size_t)Pq * 64 + h * 16 + i * 4];
    q[i*8+0] = bflo(u4.x); q[i*8+1] = bfhi(u4.x);
    q[i*8+2] = bflo(u4.y); q[i*8+3] = bfhi(u4.y);
    q[i*8+4] = bflo(u4.z); q[i*8+5] = bfhi(u4.z);
    q[i*8+6] = bflo(u4.w); q[i*8+7] = bfhi(u4.w);
  }
  __syncthreads();

  // ---- scores: 13/12/12/12 neighbors per d-group; 4 x ds_read_b128 each ----
  const float scale = 0.17677669529663687f;  // 32^-0.5
  const int nb0    = (dg == 0) ? 0 : dg * 12 + 1;
  const int ncount = (dg == 0) ? 13 : 12;
  float sreg[13];
#pragma unroll
  for (int j = 0; j < 13; ++j) {
    if (j < ncount) {
      int nb = nb0 + j;
      int dy = nb / 7 - 3;
      int dx = nb % 7 - 3;
      int ry = r + dy + 3;
      int nx = x + dx;
      int xx = min(max(nx, 0), 63);
      int ny = y0 + r + dy;
      bool valid = (ny >= 0) && (ny <= 63) && (nx >= 0) && (nx <= 63);
      const unsigned int* kb = &smem[(ry * 64 + xx) * 20];
      float acc = 0.f;
#pragma unroll
      for (int c = 0; c < 4; ++c) {
        uint4 u4 = *(const uint4*)&kb[c * 4];
        acc += q[c*8+0] * bflo(u4.x) + q[c*8+1] * bfhi(u4.x);
        acc += q[c*8+2] * bflo(u4.y) + q[c*8+3] * bfhi(u4.y);
        acc += q[c*8+4] * bflo(u4.z) + q[c*8+5] * bfhi(u4.z);
        acc += q[c*8+6] * bflo(u4.w) + q[c*8+7] * bfhi(u4.w);
      }
      sreg[j] = valid ? acc * scale : -1e30f;
    }
  }
  __syncthreads();                   // all K reads done before sS overlay
#pragma unroll
  for (int j = 0; j < 13; ++j)
    if (j < ncount) sS[(nb0 + j) * 128 + px] = sreg[j];
  __syncthreads();

  // ---- streamed softmax (fixed m=8; |s| << 8, overflow-safe) + PV (1 b128/neighbor) ----
  float o[8] = {0.f, 0.f, 0.f, 0.f, 0.f, 0.f, 0.f, 0.f};
  float sum = 0.f;
#pragma unroll
  for (int nb = 0; nb < 49; ++nb) {
    float p = __expf(sS[nb * 128 + px] - 8.0f);   // invalid -1e30 -> exp = 0
    sum += p;
    int ry = r + nb / 7;                          // nb static
    int xx = min(max(x + nb % 7 - 3, 0), 63);
    uint4 u4 = *(const uint4*)&smem[10240 + (ry * 64 + xx) * 20 + dg * 4];
    o[0] += p * bflo(u4.x); o[1] += p * bfhi(u4.x);
    o[2] += p * bflo(u4.y); o[3] += p * bfhi(u4.y);
    o[4] += p * bflo(u4.z); o[5] += p * bfhi(u4.z);
    o[6] += p * bflo(u4.w); o[7] += p * bfhi(u4.w);
  }
  float inv = 1.0f / sum;
  unsigned int pk[4];
#pragma unroll
  for (int j = 0; j < 4; ++j)
    pk[j] = f2bf(o[2*j] * inv) | (f2bf(o[2*j+1] * inv) << 16);
  *(uint4*)&ATT[(size_t)Pq * CDIM + h * HD + dg * 8] = make_uint4(pk[0], pk[1], pk[2], pk[3]);
}

// ================= tail: wo-conv + z-res + ffn-rmsnorm + ffn1 + gelu + ffn2 + res ======
// Block: 32 px, 256 thr, grid 256. ZNEW & FN live only in LDS.
__global__ __launch_bounds__(256) void tail(
    const ushort* __restrict__ ATT, const ushort* __restrict__ WB,
    const float* __restrict__ bo, const float* __restrict__ z,
    const float* __restrict__ wfn, const float* __restrict__ b1,
    const float* __restrict__ b2, float* __restrict__ out) {
  __shared__ __align__(16) float  zlds[32][132];    // fp32 ZNEW tile, padded rows
  __shared__ __align__(16) ushort fn_s[32 * 128];   // bf16 FN tile, XOR-swizzled
  __shared__ __align__(16) ushort hid_s[32 * 256];  // bf16 hidden, XOR-swizzled
  __shared__ float sums[32][17];
  __shared__ float sinv[32];
  const ushort* Wo = WB + 49152;
  const ushort* W1 = WB + 65536;
  const ushort* W2 = WB + 98304;
  const int t = threadIdx.x, w = t >> 6, l = t & 63, lr = l & 15, lk = l >> 4;
  const int pblk = blockIdx.x * 32;
  const int m0 = w * 32;

  // ---- phase A: wo GEMM (K=128), 4 waves x (32 out x 32 px) ----
  {
    const ushort* A0 = Wo + (size_t)(m0 + lr) * 128 + lk * 8;
    const ushort* A1 = A0 + 16 * 128;
    const ushort* B0 = ATT + (size_t)(pblk + lr) * 128 + lk * 8;
    const ushort* B1 = B0 + 16 * 128;
    f32x4 acc[2][2] = {};
#pragma unroll
    for (int k0 = 0; k0 < 128; k0 += 32) {
      bf16x8 a0 = *(const bf16x8*)(A0 + k0);
      bf16x8 a1 = *(const bf16x8*)(A1 + k0);
      bf16x8 b0 = *(const bf16x8*)(B0 + k0);
      bf16x8 b1 = *(const bf16x8*)(B1 + k0);
      acc[0][0] = __builtin_amdgcn_mfma_f32_16x16x32_bf16(a0, b0, acc[0][0], 0, 0, 0);
      acc[0][1] = __builtin_amdgcn_mfma_f32_16x16x32_bf16(a0, b1, acc[0][1], 0, 0, 0);
      acc[1][0] = __builtin_amdgcn_mfma_f32_16x16x32_bf16(a1, b0, acc[1][0], 0, 0, 0);
      acc[1][1] = __builtin_amdgcn_mfma_f32_16x16x32_bf16(a1, b1, acc[1][1], 0, 0, 0);
    }
    // epilogue A: u = acc + bo + z; -> zlds (float4), square-sums -> sums
#pragma unroll
    for (int nf = 0; nf < 2; ++nf) {
      int px = nf * 16 + lr;
      int P  = pblk + px;
      int b_ = P >> 12, p = P & 4095;
      float ss = 0.f;
#pragma unroll
      for (int mf = 0; mf < 2; ++mf) {
        int row0 = m0 + mf * 16 + lk * 4;
        f32x4 bv = *(const f32x4*)&bo[row0];
        f32x4 rr;
#pragma unroll
        for (int j = 0; j < 4; ++j) {
          size_t gi = ((size_t)(b_ * CDIM + row0 + j)) * HW + p;
          float u = acc[mf][nf][j] + bv[j] + z[gi];
          rr[j] = u;
          ss += u * u;
        }
        *(f32x4*)&zlds[px][row0] = rr;
      }
      sums[px][w * 4 + lk] = ss;
    }
  }
  __syncthreads();
  if (t < 32) {
    float tot = 0.f;
#pragma unroll
    for (int i = 0; i < 16; ++i) tot += sums[t][i];
    sinv[t] = rsqrtf(tot * (1.0f / CDIM) + 1e-8f);
  }
  __syncthreads();
  // ---- FN = rmsnorm(ZNEW)*wfn -> bf16 LDS (swizzled); read zlds back ----
#pragma unroll
  for (int nf = 0; nf < 2; ++nf) {
    int px = nf * 16 + lr;
    float inv = sinv[px];
#pragma unroll
    for (int mf = 0; mf < 2; ++mf) {
      int row0 = m0 + mf * 16 + lk * 4;
      f32x4 uu = *(const f32x4*)&zlds[px][row0];
      f32x4 wf = *(const f32x4*)&wfn[row0];
      uint2 pk;
      pk.x = f2bf(uu[0] * inv * wf[0]) | (f2bf(uu[1] * inv * wf[1]) << 16);
      pk.y = f2bf(uu[2] * inv * wf[2]) | (f2bf(uu[3] * inv * wf[3]) << 16);
      int idx = (px * 128 + row0) ^ ((px & 7) << 3);
      *(uint2*)&fn_s[idx] = pk;
    }
  }
  __syncthreads();
  // ---- phase B: ffn1 (K=128), 4 waves x (64 hid x 32 px); B from fn_s ----
  {
    const int hm0 = w * 64;
    const ushort* A0 = W1 + (size_t)(hm0 + lr) * 128 + lk * 8;
    f32x4 acc1[4][2] = {};
#pragma unroll
    for (int k0 = 0; k0 < 128; k0 += 32) {
      bf16x8 a[4], b[2];
#pragma unroll
      for (int mf = 0; mf < 4; ++mf) a[mf] = *(const bf16x8*)(A0 + mf * 16 * 128 + k0);
#pragma unroll
      for (int nf = 0; nf < 2; ++nf) {
        int px = nf * 16 + lr;
        b[nf] = *(const bf16x8*)&fn_s[(px * 128 + k0 + lk * 8) ^ ((px & 7) << 3)];
      }
#pragma unroll
      for (int mf = 0; mf < 4; ++mf)
#pragma unroll
        for (int nf = 0; nf < 2; ++nf)
          acc1[mf][nf] = __builtin_amdgcn_mfma_f32_16x16x32_bf16(a[mf], b[nf], acc1[mf][nf], 0, 0, 0);
    }
#pragma unroll
    for (int mf = 0; mf < 4; ++mf) {
      int ch0 = hm0 + mf * 16 + lk * 4;
      f32x4 bv = *(const f32x4*)&b1[ch0];
#pragma unroll
      for (int nf = 0; nf < 2; ++nf) {
        int px = nf * 16 + lr;
        float v0 = gelu_f(acc1[mf][nf][0] + bv[0]);
        float v1 = gelu_f(acc1[mf][nf][1] + bv[1]);
        float v2 = gelu_f(acc1[mf][nf][2] + bv[2]);
        float v3 = gelu_f(acc1[mf][nf][3] + bv[3]);
        uint2 pk;
        pk.x = f2bf(v0) | (f2bf(v1) << 16);
        pk.y = f2bf(v2) | (f2bf(v3) << 16);
        int idx = (px * 256 + ch0) ^ ((px & 7) << 3);
        *(uint2*)&hid_s[idx] = pk;
      }
    }
  }
  __syncthreads();
  // ---- phase C: ffn2 (K=256), 4 waves x (32 out x 32 px); B from hid_s; +b2 +ZNEW ----
  {
    const ushort* C0 = W2 + (size_t)(m0 + lr) * 256 + lk * 8;
    f32x4 acc2[2][2] = {};
#pragma unroll
    for (int k0 = 0; k0 < 256; k0 += 32) {
      bf16x8 a0 = *(const bf16x8*)(C0 + k0);
      bf16x8 a1 = *(const bf16x8*)(C0 + 16 * 256 + k0);
      bf16x8 b[2];
#pragma unroll
      for (int nf = 0; nf < 2; ++nf) {
        int px = nf * 16 + lr;
        b[nf] = *(const bf16x8*)&hid_s[(px * 256 + k0 + lk * 8) ^ ((px & 7) << 3)];
      }
      acc2[0][0] = __builtin_amdgcn_mfma_f32_16x16x32_bf16(a0, b[0], acc2[0][0], 0, 0, 0);
      acc2[0][1] = __builtin_amdgcn_mfma_f32_16x16x32_bf16(a0, b[1], acc2[0][1], 0, 0, 0);
      acc2[1][0] = __builtin_amdgcn_mfma_f32_16x16x32_bf16(a1, b[0], acc2[1][0], 0, 0, 0);
      acc2[1][1] = __builtin_amdgcn_mfma_f32_16x16x32_bf16(a1, b[1], acc2[1][1], 0, 0, 0);
    }
#pragma unroll
    for (int mf = 0; mf < 2; ++mf) {
      int row0 = m0 + mf * 16 + lk * 4;
      f32x4 bv = *(const f32x4*)&b2[row0];
#pragma unroll
      for (int nf = 0; nf < 2; ++nf) {
        int px = nf * 16 + lr;
        int P  = pblk + px;
        int b_ = P >> 12, p = P & 4095;
        f32x4 zz = *(const f32x4*)&zlds[px][row0];
#pragma unroll
        for (int j = 0; j < 4; ++j) {
          size_t gi = ((size_t)(b_ * CDIM + row0 + j)) * HW + p;
          out[gi] = acc2[mf][nf][j] + bv[j] + zz[j];
        }
      }
    }
  }
}

// ================= launch =================
extern "C" void kernel_launch(void* const* d_in, const int* in_sizes, int n_in,
                              void* d_out, int out_size, void* d_ws, size_t ws_size,
                              hipStream_t stream) {
  const float* z   = (const float*)d_in[0];
  const float* h   = (const float*)d_in[1];
  const float* wzn = (const float*)d_in[2];
  const float* whn = (const float*)d_in[3];
  const float* wq  = (const float*)d_in[4];
  const float* bq  = (const float*)d_in[5];
  const float* wk  = (const float*)d_in[6];
  const float* bk  = (const float*)d_in[7];
  const float* wv  = (const float*)d_in[8];
  const float* bv  = (const float*)d_in[9];
  const float* wo  = (const float*)d_in[10];
  const float* bo  = (const float*)d_in[11];
  const float* wfn = (const float*)d_in[12];
  const float* w1  = (const float*)d_in[13];
  const float* b1  = (const float*)d_in[14];
  const float* w2  = (const float*)d_in[15];
  const float* b2  = (const float*)d_in[16];
  float* out = (float*)d_out;

  const size_t U = 1048576;                  // one [8192][128] bf16 tensor (ushorts)
  ushort* Qb  = (ushort*)d_ws;
  ushort* Kb  = Qb + U;
  ushort* Vb  = Kb + U;
  ushort* ATT = Vb + U;
  ushort* WB  = ATT + U;                     // 131072 ushorts (wo/w1/w2 at +49152)

  head<<<dim3(128, 4), 256, 0, stream>>>(z, h, wzn, whn, wq, bq, wk, bk, wv, bv,
                                         wo, w1, w2, WB, Qb, Kb, Vb);
  nattn<<<dim3(32, HEADS, 2), 512, 0, stream>>>(Qb, Kb, Vb, ATT);
  tail<<<dim3(256), 256, 0, stream>>>(ATT, WB, bo, z, wfn, b1, b2, out);
}